// Round 1
// baseline (1121.166 us; speedup 1.0000x reference)
//
#include <hip/hip_runtime.h>
#include <math.h>

#define Bb 16
#define Nn 2048
#define Kk 20

// ---------------- workspace layout (bytes) ----------------
#define OFF_IDX    ((size_t)0)                    // 16*2048*20*4 = 2,621,440
#define OFF_P2MAX  (((size_t)4)  << 20)           // 16*2048*128*4 = 16,777,216
#define OFF_P2MIN  (((size_t)20) << 20)           // 16,777,216
#define OFF_STATS  (((size_t)36) << 20)
#define OFF_MOM    (OFF_STATS + 0)                // 27 double (edge moments)
#define OFF_A1C1   (OFF_STATS + 4096)             // 128 float (bn1 affine)
#define OFF_A2C2   (OFF_STATS + 8192)             // 256 float (bn2 affine)
#define OFF_S2SUM  (OFF_STATS + 12288)            // 128 double
#define OFF_S2SQ   (OFF_STATS + 16384)            // 128 double
#define OFF_S3SUM  (OFF_STATS + 20480)            // 1024 double
#define OFF_S3SQ   (OFF_STATS + 28672)            // 1024 double
#define OFF_P3MAX  (OFF_STATS + 36864)            // 16*1024 uint keys
#define OFF_P3MIN  (OFF_STATS + 102400)           // 16*1024 uint keys
#define OFF_R3     (OFF_STATS + 167936)           // 16*1024 float
#define OFF_R4     (OFF_STATS + 233472)           // 16*512 float
#define OFF_R5     (OFF_STATS + 266240)           // 16*256 float
#define WS_NEEDED  (OFF_STATS + 282624)

// ordered-uint key for float atomic max/min
__device__ __forceinline__ unsigned fkey(float f){
  unsigned u = __float_as_uint(f);
  return (u & 0x80000000u) ? ~u : (u | 0x80000000u);
}
__device__ __forceinline__ float fdec(unsigned k){
  unsigned u = (k & 0x80000000u) ? (k & 0x7FFFFFFFu) : ~k;
  return __uint_as_float(u);
}

// ---------------- K0: per-launch accumulator init ----------------
__global__ __launch_bounds__(256) void k_init(char* __restrict__ ws){
  int i = blockIdx.x*256 + threadIdx.x;
  unsigned* z = (unsigned*)(ws + OFF_MOM);
  if (i < 9216) z[i] = 0u;                       // MOM .. S3SQ (36,864 B)
  if (i < 16384){
    ((unsigned*)(ws + OFF_P3MAX))[i] = 0u;
    ((unsigned*)(ws + OFF_P3MIN))[i] = 0xFFFFFFFFu;
  }
}

// ---------------- K1: KNN top-20 + fused edge-moment accumulation ----------------
#define CAP 40
__global__ __launch_bounds__(128) void k_knn(const float* __restrict__ pc,
                                             int* __restrict__ idxg,
                                             double* __restrict__ MOM){
  __shared__ float4 pts[Nn];                      // 32 KB
  __shared__ unsigned short ibuf[128*CAP];        // 10 KB
  __shared__ float momS[27];
  const int tid = threadIdx.x;
  const int b = blockIdx.y;
  const float* pcb = pc + b*3*Nn;
  for (int i = tid; i < Nn; i += 128){
    float x = pcb[i], y = pcb[Nn+i], z = pcb[2*Nn+i];
    pts[i] = make_float4(x, y, z, x*x + y*y + z*z);
  }
  if (tid < 27) momS[tid] = 0.f;
  __syncthreads();

  const int n = blockIdx.x*128 + tid;
  const float4 Q = pts[n];
  float val[20]; int ind[20];
  #pragma unroll
  for (int t = 0; t < 20; t++){ val[t] = -3.4e38f; ind[t] = 0; }
  float minval = -3.4e38f;
  int minpos = 0, cnt = 0;
  unsigned short* mybuf = &ibuf[tid*CAP];

  auto flush = [&](){
    for (int jj = 0; jj < cnt; jj++){
      int mm = (int)mybuf[jj];
      float4 P = pts[mm];
      float nd = 2.f*(Q.x*P.x + Q.y*P.y + Q.z*P.z) - Q.w - P.w;
      if (nd > minval){
        #pragma unroll
        for (int t = 0; t < 20; t++) if (t == minpos){ val[t] = nd; ind[t] = mm; }
        minval = val[0]; minpos = 0;
        #pragma unroll
        for (int t = 1; t < 20; t++){ if (val[t] < minval){ minval = val[t]; minpos = t; } }
      }
    }
    cnt = 0;
  };

  int m0 = 0;
  #pragma unroll 1
  for (int si = 0; si < 7; si++){
    const int m1 = 32 << si;                      // 32,64,128,256,512,1024,2048
    for (int m = m0; m < m1; m++){
      float4 P = pts[m];
      float nd = 2.f*(Q.x*P.x + Q.y*P.y + Q.z*P.z) - Q.w - P.w;
      if (nd > minval){
        if (cnt == CAP) flush();
        mybuf[cnt++] = (unsigned short)m;
      }
    }
    flush();
    m0 = m1;
  }

  #pragma unroll
  for (int t = 0; t < 20; t++) idxg[((b<<11)+n)*20 + t] = ind[t];

  // fused edge-feature moments: e = [cx,cy,cz, px-cx,py-cy,pz-cz]
  float s1[6] = {0,0,0,0,0,0};
  float s2[21] = {0,0,0,0,0,0,0,0,0,0,0,0,0,0,0,0,0,0,0,0,0};
  #pragma unroll
  for (int t = 0; t < 20; t++){
    float4 P = pts[ind[t]];
    float e[6] = {Q.x, Q.y, Q.z, P.x-Q.x, P.y-Q.y, P.z-Q.z};
    int u = 0;
    #pragma unroll
    for (int c = 0; c < 6; c++){
      s1[c] += e[c];
      #pragma unroll
      for (int cp = c; cp < 6; cp++){ s2[u] += e[c]*e[cp]; u++; }
    }
  }
  #pragma unroll
  for (int c = 0; c < 6; c++) atomicAdd(&momS[c], s1[c]);
  #pragma unroll
  for (int u = 0; u < 21; u++) atomicAdd(&momS[6+u], s2[u]);
  __syncthreads();
  if (tid < 27) atomicAdd(&MOM[tid], (double)momS[tid]);
}

// ---------------- K3: bn1 affine coefficients from edge moments ----------------
__global__ __launch_bounds__(64) void k_coef1(const double* __restrict__ MOM,
        const float* __restrict__ W1, const float* __restrict__ g1,
        const float* __restrict__ b1, float* __restrict__ A1C1){
  const int o = threadIdx.x;                      // 64
  const double inv = 1.0/655360.0;
  double w[6];
  double m = 0.0;
  #pragma unroll
  for (int c = 0; c < 6; c++){ w[c] = (double)W1[c*64+o]; m += w[c]*MOM[c]*inv; }
  double e2 = 0.0;
  int u = 0;
  #pragma unroll
  for (int c = 0; c < 6; c++){
    #pragma unroll
    for (int cp = c; cp < 6; cp++){
      double mm = MOM[6+u]*inv; u++;
      e2 += (c == cp) ? w[c]*w[c]*mm : 2.0*w[c]*w[cp]*mm;
    }
  }
  double var = e2 - m*m;
  double a = (double)g1[o] / sqrt(var + 1e-5);
  A1C1[o]    = (float)a;
  A1C1[64+o] = (float)((double)b1[o] - a*m);
}

// ---------------- K4: conv1+bn1+relu+conv2, bn2 stats, max/min-pool over k ----------------
__global__ __launch_bounds__(256) void k_conv12(const float* __restrict__ pc,
      const int* __restrict__ idxg, const float* __restrict__ W1,
      const float* __restrict__ A1C1, const float* __restrict__ W2,
      double* __restrict__ S2SUM, double* __restrict__ S2SQ,
      float* __restrict__ P2MAX, float* __restrict__ P2MIN){
  __shared__ float w2s[64*128];                   // 32 KB
  __shared__ float h1s[64*160];                   // 40 KB
  __shared__ float es[6*160];                     // 3.75 KB
  __shared__ float ssum[128], ssq[128];
  const int tid = threadIdx.x;
  const int b = blockIdx.y;
  const int n0 = blockIdx.x*8;

  for (int i = tid; i < 64*128; i += 256) w2s[i] = W2[i];
  if (tid < 128){ ssum[tid] = 0.f; ssq[tid] = 0.f; }
  if (tid < 160){
    int s = tid;
    int nl = s/20, kk = s - nl*20;
    int n = n0 + nl;
    int m = idxg[((b<<11)+n)*20 + kk];
    const float* pcb = pc + b*3*Nn;
    float cx = pcb[n],  cy = pcb[Nn+n],  cz = pcb[2*Nn+n];
    float px = pcb[m],  py = pcb[Nn+m],  pz = pcb[2*Nn+m];
    es[s]       = cx;     es[160+s] = cy;     es[320+s] = cz;
    es[480+s]   = px-cx;  es[640+s] = py-cy;  es[800+s] = pz-cz;
  }
  __syncthreads();

  for (int i = tid; i < 64*160; i += 256){
    int o = i/160, s = i - o*160;
    float x = 0.f;
    #pragma unroll
    for (int c = 0; c < 6; c++) x += W1[c*64+o]*es[c*160+s];
    h1s[i] = fmaxf(A1C1[o]*x + A1C1[64+o], 0.f);
  }
  __syncthreads();

  const int pg = tid & 63, p0 = pg*2, sg = tid >> 6;
  #pragma unroll
  for (int j = 0; j < 2; j++){
    const int nl = sg + 4*j;
    const int n = n0 + nl;
    float a0[20], a1[20];
    #pragma unroll
    for (int t = 0; t < 20; t++){ a0[t] = 0.f; a1[t] = 0.f; }
    const float* hb = h1s + nl*20;
    for (int o = 0; o < 64; o++){
      float2 w = *(const float2*)&w2s[o*128 + p0];
      const float* hr = hb + o*160;
      #pragma unroll
      for (int qq = 0; qq < 5; qq++){
        float4 h = *(const float4*)(hr + qq*4);
        a0[qq*4+0] += w.x*h.x; a0[qq*4+1] += w.x*h.y; a0[qq*4+2] += w.x*h.z; a0[qq*4+3] += w.x*h.w;
        a1[qq*4+0] += w.y*h.x; a1[qq*4+1] += w.y*h.y; a1[qq*4+2] += w.y*h.z; a1[qq*4+3] += w.y*h.w;
      }
    }
    float mx0 = a0[0], mn0 = a0[0], sm0 = 0.f, sq0 = 0.f;
    float mx1 = a1[0], mn1 = a1[0], sm1 = 0.f, sq1 = 0.f;
    #pragma unroll
    for (int t = 0; t < 20; t++){
      float v0 = a0[t], v1 = a1[t];
      mx0 = fmaxf(mx0, v0); mn0 = fminf(mn0, v0); sm0 += v0; sq0 += v0*v0;
      mx1 = fmaxf(mx1, v1); mn1 = fminf(mn1, v1); sm1 += v1; sq1 += v1*v1;
    }
    size_t base = ((size_t)((b<<11)+n))*128 + (size_t)p0;
    *(float2*)&P2MAX[base] = make_float2(mx0, mx1);
    *(float2*)&P2MIN[base] = make_float2(mn0, mn1);
    atomicAdd(&ssum[p0], sm0);   atomicAdd(&ssum[p0+1], sm1);
    atomicAdd(&ssq[p0],  sq0);   atomicAdd(&ssq[p0+1],  sq1);
  }
  __syncthreads();
  if (tid < 128){
    atomicAdd(&S2SUM[tid], (double)ssum[tid]);
    atomicAdd(&S2SQ[tid],  (double)ssq[tid]);
  }
}

// ---------------- K5: bn2 affine coefficients ----------------
__global__ __launch_bounds__(128) void k_coef2(const double* __restrict__ S2SUM,
        const double* __restrict__ S2SQ, const float* __restrict__ g2,
        const float* __restrict__ b2, float* __restrict__ A2C2){
  const int p = threadIdx.x;                      // 128
  const double inv = 1.0/655360.0;
  double mean = S2SUM[p]*inv;
  double var  = S2SQ[p]*inv - mean*mean;
  double a = (double)g2[p] / sqrt(var + 1e-5);
  A2C2[p]     = (float)a;
  A2C2[128+p] = (float)((double)b2[p] - a*mean);
}

// ---------------- K6: bn2+relu (on pooled pre-BN) + conv3, bn3 stats, pool over n ----------------
__global__ __launch_bounds__(256) void k_conv3(const float* __restrict__ P2MAX,
      const float* __restrict__ P2MIN, const float* __restrict__ A2C2,
      const float* __restrict__ W3, double* __restrict__ S3SUM,
      double* __restrict__ S3SQ, unsigned* __restrict__ P3MAX,
      unsigned* __restrict__ P3MIN){
  __shared__ float r2s[128*36];                   // 18 KB (padded rows)
  __shared__ float w3s[128*64];                   // 32 KB
  __shared__ float qsum[64], qsq[64];
  __shared__ unsigned qmx[64], qmn[64];
  const int tid = threadIdx.x;
  const int b = blockIdx.y;
  const int n0 = blockIdx.x*32;

  for (int i = tid; i < 4096; i += 256){
    int p = i & 127, nl = i >> 7;
    size_t base = ((size_t)((b<<11)+n0+nl))*128 + (size_t)p;
    float mx = P2MAX[base], mn = P2MIN[base];
    float a = A2C2[p], c = A2C2[128+p];
    r2s[p*36 + nl] = fmaxf(a*((a >= 0.f) ? mx : mn) + c, 0.f);
  }
  __syncthreads();

  const int q0 = (tid & 31)*2, sg = tid >> 5, s0 = sg*4;
  for (int qb = 0; qb < 16; qb++){
    for (int i = tid; i < 8192; i += 256){
      int qq = i & 63, p = i >> 6;
      w3s[i] = W3[p*1024 + qb*64 + qq];
    }
    if (tid < 64){ qsum[tid] = 0.f; qsq[tid] = 0.f; qmx[tid] = 0u; qmn[tid] = 0xFFFFFFFFu; }
    __syncthreads();

    float acc00 = 0.f, acc01 = 0.f, acc02 = 0.f, acc03 = 0.f;
    float acc10 = 0.f, acc11 = 0.f, acc12 = 0.f, acc13 = 0.f;
    for (int o = 0; o < 128; o++){
      float2 w = *(const float2*)&w3s[o*64 + q0];
      float4 r = *(const float4*)&r2s[o*36 + s0];
      acc00 += w.x*r.x; acc01 += w.x*r.y; acc02 += w.x*r.z; acc03 += w.x*r.w;
      acc10 += w.y*r.x; acc11 += w.y*r.y; acc12 += w.y*r.z; acc13 += w.y*r.w;
    }
    {
      float s = acc00+acc01+acc02+acc03;
      float ss = acc00*acc00+acc01*acc01+acc02*acc02+acc03*acc03;
      float mx = fmaxf(fmaxf(acc00,acc01), fmaxf(acc02,acc03));
      float mn = fminf(fminf(acc00,acc01), fminf(acc02,acc03));
      atomicAdd(&qsum[q0], s); atomicAdd(&qsq[q0], ss);
      atomicMax(&qmx[q0], fkey(mx)); atomicMin(&qmn[q0], fkey(mn));
    }
    {
      float s = acc10+acc11+acc12+acc13;
      float ss = acc10*acc10+acc11*acc11+acc12*acc12+acc13*acc13;
      float mx = fmaxf(fmaxf(acc10,acc11), fmaxf(acc12,acc13));
      float mn = fminf(fminf(acc10,acc11), fminf(acc12,acc13));
      atomicAdd(&qsum[q0+1], s); atomicAdd(&qsq[q0+1], ss);
      atomicMax(&qmx[q0+1], fkey(mx)); atomicMin(&qmn[q0+1], fkey(mn));
    }
    __syncthreads();
    if (tid < 64){
      int qg = qb*64 + tid;
      atomicAdd(&S3SUM[qg], (double)qsum[tid]);
      atomicAdd(&S3SQ[qg],  (double)qsq[tid]);
      atomicMax(&P3MAX[b*1024 + qg], qmx[tid]);
      atomicMin(&P3MIN[b*1024 + qg], qmn[tid]);
    }
    __syncthreads();
  }
}

// ---------------- K7: bn3+relu applied to pooled-over-n values ----------------
__global__ __launch_bounds__(256) void k_bn3relu(const double* __restrict__ S3SUM,
      const double* __restrict__ S3SQ, const unsigned* __restrict__ P3MAX,
      const unsigned* __restrict__ P3MIN, const float* __restrict__ g3,
      const float* __restrict__ b3, float* __restrict__ R3){
  int id = blockIdx.x*256 + threadIdx.x;          // 16384
  int q = id & 1023;
  double mean = S3SUM[q] * (1.0/32768.0);
  double var  = S3SQ[q] * (1.0/32768.0) - mean*mean;
  double a = (double)g3[q] / sqrt(var + 1e-5);
  double c = (double)b3[q] - a*mean;
  float v = fdec((a >= 0.0) ? P3MAX[id] : P3MIN[id]);
  R3[id] = fmaxf((float)(a*(double)v + c), 0.f);
}

// ---------------- K8/K9: FC + batch-BN + relu (one block per out channel) ----------------
__global__ __launch_bounds__(64) void k_fc(const float* __restrict__ X,
      const float* __restrict__ W, const float* __restrict__ g,
      const float* __restrict__ bet, float* __restrict__ Y, int IN, int OUT){
  const int o = blockIdx.x, lane = threadIdx.x;
  __shared__ float dots[16];
  for (int b = 0; b < 16; b++){
    float acc = 0.f;
    for (int c = lane; c < IN; c += 64) acc += X[b*IN + c] * W[c*OUT + o];
    #pragma unroll
    for (int off = 32; off > 0; off >>= 1) acc += __shfl_down(acc, off);
    if (lane == 0) dots[b] = acc;
  }
  __syncthreads();
  if (lane < 16){
    float m = 0.f;
    #pragma unroll
    for (int b = 0; b < 16; b++) m += dots[b];
    m *= (1.f/16.f);
    float v = 0.f;
    #pragma unroll
    for (int b = 0; b < 16; b++){ float d = dots[b]-m; v += d*d; }
    v *= (1.f/16.f);
    float a = g[o] * rsqrtf(v + 1e-5f);
    Y[lane*OUT + o] = fmaxf(a*(dots[lane]-m) + bet[o], 0.f);
  }
}

// ---------------- K10: final 256->9 + bias ----------------
__global__ __launch_bounds__(192) void k_head(const float* __restrict__ R5,
      const float* __restrict__ Wf3, const float* __restrict__ bf3,
      float* __restrict__ out){
  int t = threadIdx.x;
  if (t >= 144) return;
  int b = t/9, j = t - b*9;
  float acc = bf3[j];
  for (int c = 0; c < 256; c++) acc += R5[b*256 + c]*Wf3[c*9 + j];
  out[t] = acc;
}

extern "C" void kernel_launch(void* const* d_in, const int* in_sizes, int n_in,
                              void* d_out, int out_size, void* d_ws, size_t ws_size,
                              hipStream_t stream) {
  if (ws_size < WS_NEEDED) return;   // fail loudly (output stays wrong) rather than corrupt
  const float* pc  = (const float*)d_in[0];
  const float* W1  = (const float*)d_in[1];
  const float* g1  = (const float*)d_in[2];
  const float* b1  = (const float*)d_in[3];
  const float* W2  = (const float*)d_in[4];
  const float* g2  = (const float*)d_in[5];
  const float* b2  = (const float*)d_in[6];
  const float* W3  = (const float*)d_in[7];
  const float* g3  = (const float*)d_in[8];
  const float* b3  = (const float*)d_in[9];
  const float* Wf1 = (const float*)d_in[10];
  const float* gf1 = (const float*)d_in[11];
  const float* bf1 = (const float*)d_in[12];
  const float* Wf2 = (const float*)d_in[13];
  const float* gf2 = (const float*)d_in[14];
  const float* bf2 = (const float*)d_in[15];
  const float* Wf3 = (const float*)d_in[16];
  const float* bf3 = (const float*)d_in[17];

  char* ws = (char*)d_ws;
  int*      IDX   = (int*)     (ws + OFF_IDX);
  float*    P2MAXp= (float*)   (ws + OFF_P2MAX);
  float*    P2MINp= (float*)   (ws + OFF_P2MIN);
  double*   MOMp  = (double*)  (ws + OFF_MOM);
  float*    A1C1p = (float*)   (ws + OFF_A1C1);
  float*    A2C2p = (float*)   (ws + OFF_A2C2);
  double*   S2SUMp= (double*)  (ws + OFF_S2SUM);
  double*   S2SQp = (double*)  (ws + OFF_S2SQ);
  double*   S3SUMp= (double*)  (ws + OFF_S3SUM);
  double*   S3SQp = (double*)  (ws + OFF_S3SQ);
  unsigned* P3MAXp= (unsigned*)(ws + OFF_P3MAX);
  unsigned* P3MINp= (unsigned*)(ws + OFF_P3MIN);
  float*    R3p   = (float*)   (ws + OFF_R3);
  float*    R4p   = (float*)   (ws + OFF_R4);
  float*    R5p   = (float*)   (ws + OFF_R5);

  k_init   <<<dim3(64),      256, 0, stream>>>(ws);
  k_knn    <<<dim3(16,16),   128, 0, stream>>>(pc, IDX, MOMp);
  k_coef1  <<<dim3(1),        64, 0, stream>>>(MOMp, W1, g1, b1, A1C1p);
  k_conv12 <<<dim3(256,16),  256, 0, stream>>>(pc, IDX, W1, A1C1p, W2, S2SUMp, S2SQp, P2MAXp, P2MINp);
  k_coef2  <<<dim3(1),       128, 0, stream>>>(S2SUMp, S2SQp, g2, b2, A2C2p);
  k_conv3  <<<dim3(64,16),   256, 0, stream>>>(P2MAXp, P2MINp, A2C2p, W3, S3SUMp, S3SQp, P3MAXp, P3MINp);
  k_bn3relu<<<dim3(64),      256, 0, stream>>>(S3SUMp, S3SQp, P3MAXp, P3MINp, g3, b3, R3p);
  k_fc     <<<dim3(512),      64, 0, stream>>>(R3p, Wf1, gf1, bf1, R4p, 1024, 512);
  k_fc     <<<dim3(256),      64, 0, stream>>>(R4p, Wf2, gf2, bf2, R5p, 512, 256);
  k_head   <<<dim3(1),       192, 0, stream>>>(R5p, Wf3, bf3, (float*)d_out);
}

// Round 2
// 412.025 us; speedup vs baseline: 2.7211x; 2.7211x over previous
//
#include <hip/hip_runtime.h>
#include <math.h>

#define Nn 2048

// ---------------- workspace layout (bytes) ----------------
#define OFF_IDX    ((size_t)0)                    // 16*2048*20*4
#define OFF_P2MAX  (((size_t)4)  << 20)           // 16*2048*128*4
#define OFF_P2MIN  (((size_t)20) << 20)
#define OFF_STATS  (((size_t)36) << 20)
#define OFF_MOM    (OFF_STATS + 0)                // 27 double
#define OFF_A1C1   (OFF_STATS + 4096)             // 128 float
#define OFF_A2C2   (OFF_STATS + 8192)             // 256 float
#define OFF_S2SUM  (OFF_STATS + 12288)            // 128 double
#define OFF_S2SQ   (OFF_STATS + 16384)            // 128 double
#define OFF_S3SUM  (OFF_STATS + 20480)            // 1024 double
#define OFF_S3SQ   (OFF_STATS + 28672)            // 1024 double
#define OFF_P3MAX  (OFF_STATS + 36864)            // 16*1024 uint
#define OFF_P3MIN  (OFF_STATS + 102400)           // 16*1024 uint
#define OFF_R3     (OFF_STATS + 167936)           // 16*1024 float
#define OFF_R4     (OFF_STATS + 233472)           // 16*512 float
#define OFF_R5     (OFF_STATS + 266240)           // 16*256 float
#define OFF_DOTS1  (OFF_STATS + 282624)           // 16*512 float
#define OFF_DOTS2  (OFF_STATS + 315392)           // 16*256 float
#define WS_NEEDED  (OFF_STATS + 331776)

typedef __attribute__((ext_vector_type(8))) short bf16x8;
typedef __attribute__((ext_vector_type(4))) float f32x4;

__device__ __forceinline__ unsigned fkey(float f){
  unsigned u = __float_as_uint(f);
  return (u & 0x80000000u) ? ~u : (u | 0x80000000u);
}
__device__ __forceinline__ float fdec(unsigned k){
  unsigned u = (k & 0x80000000u) ? (k & 0x7FFFFFFFu) : ~k;
  return __uint_as_float(u);
}
__device__ __forceinline__ short f2bf(float x){
  unsigned u = __float_as_uint(x);
  u += 0x7fffu + ((u >> 16) & 1u);                // RNE
  return (short)(u >> 16);
}
__device__ __forceinline__ float med3(float a, float b, float c){
  float d;
  asm("v_med3_f32 %0, %1, %2, %3" : "=v"(d) : "v"(a), "v"(b), "v"(c));
  return d;
}
__device__ __forceinline__ float ndist(float tQx, float tQy, float tQz, float Qw, float4 P){
  return tQx*P.x + tQy*P.y + tQz*P.z - Qw - P.w;  // same expr both passes -> identical codegen
}

// ---------------- K0: per-launch accumulator init ----------------
__global__ __launch_bounds__(256) void k_init(char* __restrict__ ws){
  int i = blockIdx.x*256 + threadIdx.x;
  if (i < 9216) ((unsigned*)(ws + OFF_MOM))[i] = 0u;       // MOM..S3SQ
  if (i < 16384){
    ((unsigned*)(ws + OFF_P3MAX))[i] = 0u;
    ((unsigned*)(ws + OFF_P3MIN))[i] = 0xFFFFFFFFu;
  }
  if (i < 12288) ((float*)(ws + OFF_DOTS1))[i] = 0.f;      // DOTS1+DOTS2
}

// ---------------- K1: KNN top-20, branch-free med3 selection ----------------
// grid (32, 16), block 256. 4 threads per query, 512 candidates each.
__global__ __launch_bounds__(256) void k_knn(const float* __restrict__ pc,
                                             int* __restrict__ idxg,
                                             double* __restrict__ MOM){
  __shared__ float4 pts[Nn];           // 32 KB
  __shared__ float vbuf[64*81];        // 20.7 KB (81 stride breaks bank aliasing)
  __shared__ float theta[64];
  __shared__ unsigned cnt[64];
  __shared__ float momS[27];
  const int tid = threadIdx.x;
  const int b = blockIdx.y;
  const int n0 = blockIdx.x*64;
  const float* pcb = pc + b*3*Nn;
  for (int i = tid; i < Nn; i += 256){
    float x = pcb[i], y = pcb[Nn+i], z = pcb[2*Nn+i];
    pts[i] = make_float4(x, y, z, x*x + y*y + z*z);
  }
  if (tid < 64) cnt[tid] = 0u;
  if (tid < 27) momS[tid] = 0.f;
  __syncthreads();

  const int ql = tid >> 2, c = tid & 3;
  const int n = n0 + ql;
  const float4 Q = pts[n];
  const float tQx = 2.f*Q.x, tQy = 2.f*Q.y, tQz = 2.f*Q.z;

  // pass 1: per-thread sorted top-20 (ascending) of its 512 candidates
  float v[20];
  #pragma unroll
  for (int t = 0; t < 20; t++) v[t] = -3.4e38f;
  for (int i = 0; i < 512; i++){
    float4 P = pts[i*4 + c];
    float nd = ndist(tQx, tQy, tQz, Q.w, P);
    #pragma unroll
    for (int t = 0; t < 19; t++) v[t] = med3(v[t], v[t+1], nd);
    v[19] = fmaxf(v[19], nd);
  }
  #pragma unroll
  for (int t = 0; t < 20; t++) vbuf[ql*81 + c*20 + t] = v[t];
  __syncthreads();

  // merge 4x20 -> 20th-largest value (threshold)
  if (tid < 64){
    float m20[20];
    #pragma unroll
    for (int t = 0; t < 20; t++) m20[t] = vbuf[tid*81 + t];
    for (int j = 20; j < 80; j++){
      float x = vbuf[tid*81 + j];
      #pragma unroll
      for (int t = 0; t < 19; t++) m20[t] = med3(m20[t], m20[t+1], x);
      m20[19] = fmaxf(m20[19], x);
    }
    theta[tid] = m20[0];
  }
  __syncthreads();

  // pass 2: collect indices with nd >= theta; fuse edge-moment accumulation
  const float th = theta[ql];
  float s1[6] = {0,0,0,0,0,0};
  float s2[21] = {0,0,0,0,0,0,0,0,0,0,0,0,0,0,0,0,0,0,0,0,0};
  for (int i = 0; i < 512; i++){
    int m = i*4 + c;
    float4 P = pts[m];
    float nd = ndist(tQx, tQy, tQz, Q.w, P);
    if (nd >= th){
      unsigned pos = atomicAdd(&cnt[ql], 1u);
      if (pos < 20u){
        idxg[((size_t)((b<<11) + n))*20 + pos] = m;
        float e[6] = {Q.x, Q.y, Q.z, P.x - Q.x, P.y - Q.y, P.z - Q.z};
        int u = 0;
        #pragma unroll
        for (int a = 0; a < 6; a++){
          s1[a] += e[a];
          #pragma unroll
          for (int bq = a; bq < 6; bq++){ s2[u] += e[a]*e[bq]; u++; }
        }
      }
    }
  }
  // wave-reduce 27 accumulators, then LDS, then global double atomics
  #pragma unroll
  for (int a = 0; a < 6; a++)
    for (int off = 32; off > 0; off >>= 1) s1[a] += __shfl_xor(s1[a], off);
  #pragma unroll
  for (int u = 0; u < 21; u++)
    for (int off = 32; off > 0; off >>= 1) s2[u] += __shfl_xor(s2[u], off);
  if ((tid & 63) == 0){
    #pragma unroll
    for (int a = 0; a < 6; a++) atomicAdd(&momS[a], s1[a]);
    #pragma unroll
    for (int u = 0; u < 21; u++) atomicAdd(&momS[6+u], s2[u]);
  }
  __syncthreads();
  if (tid < 27) atomicAdd(&MOM[tid], (double)momS[tid]);
}

// ---------------- K3: bn1 affine from edge moments ----------------
__global__ __launch_bounds__(64) void k_coef1(const double* __restrict__ MOM,
        const float* __restrict__ W1, const float* __restrict__ g1,
        const float* __restrict__ b1, float* __restrict__ A1C1){
  const int o = threadIdx.x;
  const double inv = 1.0/655360.0;
  double w[6]; double m = 0.0;
  #pragma unroll
  for (int c = 0; c < 6; c++){ w[c] = (double)W1[c*64+o]; m += w[c]*MOM[c]*inv; }
  double e2 = 0.0; int u = 0;
  #pragma unroll
  for (int c = 0; c < 6; c++){
    #pragma unroll
    for (int cp = c; cp < 6; cp++){
      double mm = MOM[6+u]*inv; u++;
      e2 += (c == cp) ? w[c]*w[c]*mm : 2.0*w[c]*w[cp]*mm;
    }
  }
  double var = e2 - m*m;
  double a = (double)g1[o] / sqrt(var + 1e-5);
  A1C1[o]    = (float)a;
  A1C1[64+o] = (float)((double)b1[o] - a*m);
}

// ---------------- K4: conv1+bn1+relu+conv2, bn2 stats, k-pool (4ch x 20s tiles) ----------------
__global__ __launch_bounds__(256) void k_conv12(const float* __restrict__ pc,
      const int* __restrict__ idxg, const float* __restrict__ W1,
      const float* __restrict__ A1C1, const float* __restrict__ W2,
      double* __restrict__ S2SUM, double* __restrict__ S2SQ,
      float* __restrict__ P2MAX, float* __restrict__ P2MIN){
  __shared__ float w2s[64*128];
  __shared__ float h1s[64*160];
  __shared__ float es[6*160];
  __shared__ float ssum[128], ssq[128];
  const int tid = threadIdx.x;
  const int b = blockIdx.y;
  const int n0 = blockIdx.x*8;

  for (int i = tid; i < 64*128; i += 256) w2s[i] = W2[i];
  if (tid < 128){ ssum[tid] = 0.f; ssq[tid] = 0.f; }
  if (tid < 160){
    int s = tid;
    int nl = s/20, kk = s - nl*20;
    int n = n0 + nl;
    int m = idxg[((size_t)((b<<11)+n))*20 + kk];
    const float* pcb = pc + b*3*Nn;
    float cx = pcb[n],  cy = pcb[Nn+n],  cz = pcb[2*Nn+n];
    float px = pcb[m],  py = pcb[Nn+m],  pz = pcb[2*Nn+m];
    es[s]       = cx;     es[160+s] = cy;     es[320+s] = cz;
    es[480+s]   = px-cx;  es[640+s] = py-cy;  es[800+s] = pz-cz;
  }
  __syncthreads();

  for (int i = tid; i < 64*160; i += 256){
    int o = i/160, s = i - o*160;
    float x = 0.f;
    #pragma unroll
    for (int c = 0; c < 6; c++) x += W1[c*64+o]*es[c*160+s];
    h1s[i] = fmaxf(A1C1[o]*x + A1C1[64+o], 0.f);
  }
  __syncthreads();

  const int cg = tid & 31, p0 = cg*4, sg = tid >> 5;   // sg = local query
  float acc[4][20];
  #pragma unroll
  for (int jj = 0; jj < 4; jj++)
    #pragma unroll
    for (int t = 0; t < 20; t++) acc[jj][t] = 0.f;

  #pragma unroll 2
  for (int o = 0; o < 64; o++){
    float4 w = *(const float4*)&w2s[o*128 + p0];
    const float* hr = &h1s[o*160 + sg*20];
    float wj[4] = {w.x, w.y, w.z, w.w};
    #pragma unroll
    for (int qq = 0; qq < 5; qq++){
      float4 h = *(const float4*)&hr[qq*4];
      float hv[4] = {h.x, h.y, h.z, h.w};
      #pragma unroll
      for (int jj = 0; jj < 4; jj++)
        #pragma unroll
        for (int r = 0; r < 4; r++)
          acc[jj][qq*4+r] += wj[jj]*hv[r];
    }
  }

  float mx[4], mn[4], sm[4], sq[4];
  #pragma unroll
  for (int jj = 0; jj < 4; jj++){
    mx[jj] = acc[jj][0]; mn[jj] = acc[jj][0]; sm[jj] = 0.f; sq[jj] = 0.f;
    #pragma unroll
    for (int t = 0; t < 20; t++){
      float vv = acc[jj][t];
      mx[jj] = fmaxf(mx[jj], vv); mn[jj] = fminf(mn[jj], vv);
      sm[jj] += vv; sq[jj] += vv*vv;
    }
  }
  const int n = n0 + sg;
  size_t base = ((size_t)(b*Nn + n))*128 + (size_t)p0;
  *(float4*)&P2MAX[base] = make_float4(mx[0], mx[1], mx[2], mx[3]);
  *(float4*)&P2MIN[base] = make_float4(mn[0], mn[1], mn[2], mn[3]);
  #pragma unroll
  for (int jj = 0; jj < 4; jj++){
    atomicAdd(&ssum[p0+jj], sm[jj]);
    atomicAdd(&ssq[p0+jj],  sq[jj]);
  }
  __syncthreads();
  if (tid < 128){
    atomicAdd(&S2SUM[tid], (double)ssum[tid]);
    atomicAdd(&S2SQ[tid],  (double)ssq[tid]);
  }
}

// ---------------- K5: bn2 affine ----------------
__global__ __launch_bounds__(128) void k_coef2(const double* __restrict__ S2SUM,
        const double* __restrict__ S2SQ, const float* __restrict__ g2,
        const float* __restrict__ b2, float* __restrict__ A2C2){
  const int p = threadIdx.x;
  const double inv = 1.0/655360.0;
  double mean = S2SUM[p]*inv;
  double var  = S2SQ[p]*inv - mean*mean;
  double a = (double)g2[p] / sqrt(var + 1e-5);
  A2C2[p]     = (float)a;
  A2C2[128+p] = (float)((double)b2[p] - a*mean);
}

// ---------------- K6: bn2+relu + conv3 via MFMA bf16; bn3 stats + n-pool fused ----------------
// grid (16, 16, 2): 128-row s-tile per block, 512-col q-half, block 256.
__global__ __launch_bounds__(256) void k_conv3(const float* __restrict__ P2MAX,
      const float* __restrict__ P2MIN, const float* __restrict__ A2C2,
      const float* __restrict__ W3, double* __restrict__ S3SUM,
      double* __restrict__ S3SQ, unsigned* __restrict__ P3MAX,
      unsigned* __restrict__ P3MIN){
  __shared__ short As[128*128];        // bf16 A = r2, chunk-XOR-swizzled
  __shared__ float a2[128], c2[128];
  const int tid = threadIdx.x;
  const int b = blockIdx.y;
  const int n0 = blockIdx.x*128;
  const int qh = blockIdx.z;
  if (tid < 128){ a2[tid] = A2C2[tid]; c2[tid] = A2C2[128+tid]; }
  __syncthreads();

  // stage A: r2[s][o] bf16, 16B chunk index XOR (s&7)
  for (int idx = tid; idx < 2048; idx += 256){
    int s = idx >> 4, oc = idx & 15;
    size_t base = ((size_t)(b*Nn + n0 + s))*128 + (size_t)(oc*8);
    bf16x8 vv;
    #pragma unroll
    for (int j = 0; j < 8; j++){
      int o = oc*8 + j;
      float mxv = P2MAX[base + j];
      float mnv = P2MIN[base + j];
      float aa = a2[o];
      float rr = fmaxf(aa * ((aa >= 0.f) ? mxv : mnv) + c2[o], 0.f);
      vv[j] = f2bf(rr);
    }
    int chunk = oc ^ (s & 7);
    *(bf16x8*)&As[s*128 + chunk*8] = vv;
  }
  __syncthreads();

  const int l = tid & 63, wv = tid >> 6;
  const int col = l & 15, kc = l >> 4;     // B frag: col = lane&15, k-chunk = lane>>4

  #pragma unroll 1
  for (int pass = 0; pass < 2; ++pass){
    // B fragments in registers: 4 q-tiles x 4 k-steps
    bf16x8 Bf[4][4];
    #pragma unroll
    for (int qt = 0; qt < 4; qt++){
      int q = qh*512 + wv*128 + pass*64 + qt*16 + col;
      #pragma unroll
      for (int ks = 0; ks < 4; ks++){
        int k0 = ks*32 + kc*8;
        #pragma unroll
        for (int j = 0; j < 8; j++)
          Bf[qt][ks][j] = f2bf(W3[(size_t)(k0+j)*1024 + q]);
      }
    }
    float smx[4], smn[4], ssm[4], ssqv[4];
    #pragma unroll
    for (int qt = 0; qt < 4; qt++){ smx[qt] = -3.4e38f; smn[qt] = 3.4e38f; ssm[qt] = 0.f; ssqv[qt] = 0.f; }

    #pragma unroll 1
    for (int st = 0; st < 8; ++st){
      bf16x8 Af[4];
      int row = st*16 + (l & 15);          // A frag: row = lane&15, k-chunk = lane>>4
      #pragma unroll
      for (int ks = 0; ks < 4; ks++){
        int chunk = (ks*4 + kc) ^ (l & 7);
        Af[ks] = *(const bf16x8*)&As[row*128 + chunk*8];
      }
      #pragma unroll
      for (int qt = 0; qt < 4; qt++){
        f32x4 acc = {0.f, 0.f, 0.f, 0.f};
        #pragma unroll
        for (int ks = 0; ks < 4; ks++)
          acc = __builtin_amdgcn_mfma_f32_16x16x32_bf16(Af[ks], Bf[qt][ks], acc, 0, 0, 0);
        #pragma unroll
        for (int r = 0; r < 4; r++){
          float vv = acc[r];
          smx[qt] = fmaxf(smx[qt], vv); smn[qt] = fminf(smn[qt], vv);
          ssm[qt] += vv; ssqv[qt] += vv*vv;
        }
      }
    }
    // reduce across k-chunk lanes (rows) and emit
    #pragma unroll
    for (int qt = 0; qt < 4; qt++){
      #pragma unroll
      for (int off = 16; off <= 32; off <<= 1){
        smx[qt] = fmaxf(smx[qt], __shfl_xor(smx[qt], off));
        smn[qt] = fminf(smn[qt], __shfl_xor(smn[qt], off));
        ssm[qt] += __shfl_xor(ssm[qt], off);
        ssqv[qt] += __shfl_xor(ssqv[qt], off);
      }
    }
    if (kc == 0){
      #pragma unroll
      for (int qt = 0; qt < 4; qt++){
        int q = qh*512 + wv*128 + pass*64 + qt*16 + col;
        atomicMax(&P3MAX[b*1024 + q], fkey(smx[qt]));
        atomicMin(&P3MIN[b*1024 + q], fkey(smn[qt]));
        atomicAdd(&S3SUM[q], (double)ssm[qt]);
        atomicAdd(&S3SQ[q],  (double)ssqv[qt]);
      }
    }
  }
}

// ---------------- K7: bn3+relu on pooled values ----------------
__global__ __launch_bounds__(256) void k_bn3relu(const double* __restrict__ S3SUM,
      const double* __restrict__ S3SQ, const unsigned* __restrict__ P3MAX,
      const unsigned* __restrict__ P3MIN, const float* __restrict__ g3,
      const float* __restrict__ b3, float* __restrict__ R3){
  int id = blockIdx.x*256 + threadIdx.x;          // 16384
  int q = id & 1023;
  double mean = S3SUM[q] * (1.0/32768.0);
  double var  = S3SQ[q] * (1.0/32768.0) - mean*mean;
  double a = (double)g3[q] / sqrt(var + 1e-5);
  double c = (double)b3[q] - a*mean;
  float v = fdec((a >= 0.0) ? P3MAX[id] : P3MIN[id]);
  R3[id] = fmaxf((float)(a*(double)v + c), 0.f);
}

// ---------------- FC: partial dots (coalesced W) + BN ----------------
template<int IN, int OUT>
__global__ __launch_bounds__(256) void k_fcdot(const float* __restrict__ X,
      const float* __restrict__ W, float* __restrict__ dots){
  constexpr int L = IN/16;
  __shared__ float Xs[16*L];
  const int tid = threadIdx.x;
  const int o = blockIdx.x*64 + (tid & 63);
  const int wv = tid >> 6;
  const int c0 = blockIdx.y*L;
  for (int i = tid; i < 16*L; i += 256){
    int bb = i / L, cc = i - bb*L;
    Xs[i] = X[bb*IN + c0 + cc];
  }
  __syncthreads();
  constexpr int CPW = L/4;
  float acc[16];
  #pragma unroll
  for (int bb = 0; bb < 16; bb++) acc[bb] = 0.f;
  for (int cc = wv*CPW; cc < (wv+1)*CPW; ++cc){
    float w = W[(size_t)(c0+cc)*OUT + o];
    #pragma unroll
    for (int bb = 0; bb < 16; bb++) acc[bb] += Xs[bb*L + cc]*w;
  }
  #pragma unroll
  for (int bb = 0; bb < 16; bb++) atomicAdd(&dots[bb*OUT + o], acc[bb]);
}

template<int OUT>
__global__ __launch_bounds__(64) void k_fcbn(const float* __restrict__ dots,
      const float* __restrict__ g, const float* __restrict__ bet,
      float* __restrict__ Y){
  const int o = blockIdx.x*64 + threadIdx.x;
  float d[16]; float m = 0.f;
  #pragma unroll
  for (int bb = 0; bb < 16; bb++){ d[bb] = dots[bb*OUT + o]; m += d[bb]; }
  m *= (1.f/16.f);
  float v = 0.f;
  #pragma unroll
  for (int bb = 0; bb < 16; bb++){ float x = d[bb]-m; v += x*x; }
  v *= (1.f/16.f);
  float a = g[o] * rsqrtf(v + 1e-5f);
  #pragma unroll
  for (int bb = 0; bb < 16; bb++) Y[bb*OUT + o] = fmaxf(a*(d[bb]-m) + bet[o], 0.f);
}

// ---------------- K10: final 256->9 + bias ----------------
__global__ __launch_bounds__(192) void k_head(const float* __restrict__ R5,
      const float* __restrict__ Wf3, const float* __restrict__ bf3,
      float* __restrict__ out){
  int t = threadIdx.x;
  if (t >= 144) return;
  int b = t/9, j = t - b*9;
  float acc = bf3[j];
  for (int c = 0; c < 256; c++) acc += R5[b*256 + c]*Wf3[c*9 + j];
  out[t] = acc;
}

extern "C" void kernel_launch(void* const* d_in, const int* in_sizes, int n_in,
                              void* d_out, int out_size, void* d_ws, size_t ws_size,
                              hipStream_t stream) {
  if (ws_size < WS_NEEDED) return;
  const float* pc  = (const float*)d_in[0];
  const float* W1  = (const float*)d_in[1];
  const float* g1  = (const float*)d_in[2];
  const float* b1  = (const float*)d_in[3];
  const float* W2  = (const float*)d_in[4];
  const float* g2  = (const float*)d_in[5];
  const float* b2  = (const float*)d_in[6];
  const float* W3  = (const float*)d_in[7];
  const float* g3  = (const float*)d_in[8];
  const float* b3  = (const float*)d_in[9];
  const float* Wf1 = (const float*)d_in[10];
  const float* gf1 = (const float*)d_in[11];
  const float* bf1 = (const float*)d_in[12];
  const float* Wf2 = (const float*)d_in[13];
  const float* gf2 = (const float*)d_in[14];
  const float* bf2 = (const float*)d_in[15];
  const float* Wf3 = (const float*)d_in[16];
  const float* bf3 = (const float*)d_in[17];

  char* ws = (char*)d_ws;
  int*      IDX   = (int*)     (ws + OFF_IDX);
  float*    P2MAXp= (float*)   (ws + OFF_P2MAX);
  float*    P2MINp= (float*)   (ws + OFF_P2MIN);
  double*   MOMp  = (double*)  (ws + OFF_MOM);
  float*    A1C1p = (float*)   (ws + OFF_A1C1);
  float*    A2C2p = (float*)   (ws + OFF_A2C2);
  double*   S2SUMp= (double*)  (ws + OFF_S2SUM);
  double*   S2SQp = (double*)  (ws + OFF_S2SQ);
  double*   S3SUMp= (double*)  (ws + OFF_S3SUM);
  double*   S3SQp = (double*)  (ws + OFF_S3SQ);
  unsigned* P3MAXp= (unsigned*)(ws + OFF_P3MAX);
  unsigned* P3MINp= (unsigned*)(ws + OFF_P3MIN);
  float*    R3p   = (float*)   (ws + OFF_R3);
  float*    R4p   = (float*)   (ws + OFF_R4);
  float*    R5p   = (float*)   (ws + OFF_R5);
  float*    DOTS1p= (float*)   (ws + OFF_DOTS1);
  float*    DOTS2p= (float*)   (ws + OFF_DOTS2);

  k_init          <<<dim3(64),       256, 0, stream>>>(ws);
  k_knn           <<<dim3(32,16),    256, 0, stream>>>(pc, IDX, MOMp);
  k_coef1         <<<dim3(1),         64, 0, stream>>>(MOMp, W1, g1, b1, A1C1p);
  k_conv12        <<<dim3(256,16),   256, 0, stream>>>(pc, IDX, W1, A1C1p, W2, S2SUMp, S2SQp, P2MAXp, P2MINp);
  k_coef2         <<<dim3(1),        128, 0, stream>>>(S2SUMp, S2SQp, g2, b2, A2C2p);
  k_conv3         <<<dim3(16,16,2),  256, 0, stream>>>(P2MAXp, P2MINp, A2C2p, W3, S3SUMp, S3SQp, P3MAXp, P3MINp);
  k_bn3relu       <<<dim3(64),       256, 0, stream>>>(S3SUMp, S3SQp, P3MAXp, P3MINp, g3, b3, R3p);
  k_fcdot<1024,512><<<dim3(8,16),    256, 0, stream>>>(R3p, Wf1, DOTS1p);
  k_fcbn<512>     <<<dim3(8),         64, 0, stream>>>(DOTS1p, gf1, bf1, R4p);
  k_fcdot<512,256><<<dim3(4,16),     256, 0, stream>>>(R4p, Wf2, DOTS2p);
  k_fcbn<256>     <<<dim3(4),         64, 0, stream>>>(DOTS2p, gf2, bf2, R5p);
  k_head          <<<dim3(1),        192, 0, stream>>>(R5p, Wf3, bf3, (float*)d_out);
}

// Round 3
// 294.955 us; speedup vs baseline: 3.8011x; 1.3969x over previous
//
#include <hip/hip_runtime.h>
#include <math.h>

#define Nn 2048

// ---------------- workspace layout (bytes) ----------------
#define OFF_IDX    ((size_t)0)                    // 16*2048*20*4 = 2.62 MB
#define OFF_P2MAX  (((size_t)4)  << 20)           // 16*2048*128*2 = 8.39 MB (bf16)
#define OFF_P2MIN  (((size_t)13) << 20)           // 8.39 MB (bf16)
#define OFF_PS2    (((size_t)22) << 20)           // 128*2048 float = 1 MB
#define OFF_PQ2    (((size_t)23) << 20)           // 1 MB
#define OFF_STATS  (((size_t)24) << 20)
#define OFF_MOM    (OFF_STATS + 0)                // 27 double
#define OFF_A1C1   (OFF_STATS + 4096)             // 448 float (folded W1 + bias)
#define OFF_A2C2   (OFF_STATS + 8192)             // 256 float
#define OFF_S3SUM  (OFF_STATS + 12288)            // 1024 double
#define OFF_S3SQ   (OFF_STATS + 20480)            // 1024 double
#define OFF_P3MAX  (OFF_STATS + 28672)            // 16*1024 uint
#define OFF_P3MIN  (OFF_STATS + 94208)            // 16*1024 uint
#define OFF_R3     (OFF_STATS + 159744)           // 16*1024 float
#define OFF_R4     (OFF_STATS + 225280)           // 16*512 float
#define OFF_R5     (OFF_STATS + 258048)           // 16*256 float
#define OFF_DOTS1  (OFF_STATS + 274432)           // 16*512 float
#define OFF_DOTS2  (OFF_STATS + 307200)           // 16*256 float
#define WS_NEEDED  (OFF_STATS + 323584)

typedef __attribute__((ext_vector_type(8))) short bf16x8;
typedef __attribute__((ext_vector_type(4))) float f32x4;

__device__ __forceinline__ unsigned fkey(float f){
  unsigned u = __float_as_uint(f);
  return (u & 0x80000000u) ? ~u : (u | 0x80000000u);
}
__device__ __forceinline__ float fdec(unsigned k){
  unsigned u = (k & 0x80000000u) ? (k & 0x7FFFFFFFu) : ~k;
  return __uint_as_float(u);
}
__device__ __forceinline__ short f2bf(float x){
  unsigned u = __float_as_uint(x);
  u += 0x7fffu + ((u >> 16) & 1u);                // RNE
  return (short)(u >> 16);
}
__device__ __forceinline__ float bf2f(short v){
  return __uint_as_float(((unsigned)(unsigned short)v) << 16);
}
__device__ __forceinline__ float med3(float a, float b, float c){
  float d;
  asm("v_med3_f32 %0, %1, %2, %3" : "=v"(d) : "v"(a), "v"(b), "v"(c));
  return d;
}
__device__ __forceinline__ float ndist(float tQx, float tQy, float tQz, float Qw, float4 P){
  return tQx*P.x + tQy*P.y + tQz*P.z - Qw - P.w;  // same expr both passes -> identical codegen
}

// ---------------- K0: per-launch accumulator init ----------------
__global__ __launch_bounds__(256) void k_init(char* __restrict__ ws){
  int i = blockIdx.x*256 + threadIdx.x;
  if (i < 7168) ((unsigned*)(ws + OFF_MOM))[i] = 0u;       // MOM..S3SQ (28,672 B)
  if (i < 16384){
    ((unsigned*)(ws + OFF_P3MAX))[i] = 0u;
    ((unsigned*)(ws + OFF_P3MIN))[i] = 0xFFFFFFFFu;
  }
  if (i < 12288) ((float*)(ws + OFF_DOTS1))[i] = 0.f;      // DOTS1+DOTS2
}

// ---------------- K1: KNN top-20, branch-free med3 selection ----------------
__global__ __launch_bounds__(256) void k_knn(const float* __restrict__ pc,
                                             int* __restrict__ idxg,
                                             double* __restrict__ MOM){
  __shared__ float4 pts[Nn];           // 32 KB
  __shared__ float vbuf[64*81];        // 20.7 KB
  __shared__ float theta[64];
  __shared__ unsigned cnt[64];
  __shared__ float momS[27];
  const int tid = threadIdx.x;
  const int b = blockIdx.y;
  const int n0 = blockIdx.x*64;
  const float* pcb = pc + b*3*Nn;
  for (int i = tid; i < Nn; i += 256){
    float x = pcb[i], y = pcb[Nn+i], z = pcb[2*Nn+i];
    pts[i] = make_float4(x, y, z, x*x + y*y + z*z);
  }
  if (tid < 64) cnt[tid] = 0u;
  if (tid < 27) momS[tid] = 0.f;
  __syncthreads();

  const int ql = tid >> 2, c = tid & 3;
  const int n = n0 + ql;
  const float4 Q = pts[n];
  const float tQx = 2.f*Q.x, tQy = 2.f*Q.y, tQz = 2.f*Q.z;

  float v[20];
  #pragma unroll
  for (int t = 0; t < 20; t++) v[t] = -3.4e38f;
  for (int i = 0; i < 512; i++){
    float4 P = pts[i*4 + c];
    float nd = ndist(tQx, tQy, tQz, Q.w, P);
    #pragma unroll
    for (int t = 0; t < 19; t++) v[t] = med3(v[t], v[t+1], nd);
    v[19] = fmaxf(v[19], nd);
  }
  #pragma unroll
  for (int t = 0; t < 20; t++) vbuf[ql*81 + c*20 + t] = v[t];
  __syncthreads();

  if (tid < 64){
    float m20[20];
    #pragma unroll
    for (int t = 0; t < 20; t++) m20[t] = vbuf[tid*81 + t];
    for (int j = 20; j < 80; j++){
      float x = vbuf[tid*81 + j];
      #pragma unroll
      for (int t = 0; t < 19; t++) m20[t] = med3(m20[t], m20[t+1], x);
      m20[19] = fmaxf(m20[19], x);
    }
    theta[tid] = m20[0];
  }
  __syncthreads();

  const float th = theta[ql];
  float s1[6] = {0,0,0,0,0,0};
  float s2[21] = {0,0,0,0,0,0,0,0,0,0,0,0,0,0,0,0,0,0,0,0,0};
  for (int i = 0; i < 512; i++){
    int m = i*4 + c;
    float4 P = pts[m];
    float nd = ndist(tQx, tQy, tQz, Q.w, P);
    if (nd >= th){
      unsigned pos = atomicAdd(&cnt[ql], 1u);
      if (pos < 20u){
        idxg[((size_t)((b<<11) + n))*20 + pos] = m;
        float e[6] = {Q.x, Q.y, Q.z, P.x - Q.x, P.y - Q.y, P.z - Q.z};
        int u = 0;
        #pragma unroll
        for (int a = 0; a < 6; a++){
          s1[a] += e[a];
          #pragma unroll
          for (int bq = a; bq < 6; bq++){ s2[u] += e[a]*e[bq]; u++; }
        }
      }
    }
  }
  #pragma unroll
  for (int a = 0; a < 6; a++)
    for (int off = 32; off > 0; off >>= 1) s1[a] += __shfl_xor(s1[a], off);
  #pragma unroll
  for (int u = 0; u < 21; u++)
    for (int off = 32; off > 0; off >>= 1) s2[u] += __shfl_xor(s2[u], off);
  if ((tid & 63) == 0){
    #pragma unroll
    for (int a = 0; a < 6; a++) atomicAdd(&momS[a], s1[a]);
    #pragma unroll
    for (int u = 0; u < 21; u++) atomicAdd(&momS[6+u], s2[u]);
  }
  __syncthreads();
  if (tid < 27) atomicAdd(&MOM[tid], (double)momS[tid]);
}

// ---------------- K3: bn1 affine folded into W1 ----------------
// A1C1 out: [0..383] = a1[o]*W1[c][o] (c-major), [384..447] = c1 bias
__global__ __launch_bounds__(64) void k_coef1(const double* __restrict__ MOM,
        const float* __restrict__ W1, const float* __restrict__ g1,
        const float* __restrict__ b1, float* __restrict__ A1C1){
  const int o = threadIdx.x;
  const double inv = 1.0/655360.0;
  double w[6]; double m = 0.0;
  #pragma unroll
  for (int c = 0; c < 6; c++){ w[c] = (double)W1[c*64+o]; m += w[c]*MOM[c]*inv; }
  double e2 = 0.0; int u = 0;
  #pragma unroll
  for (int c = 0; c < 6; c++){
    #pragma unroll
    for (int cp = c; cp < 6; cp++){
      double mm = MOM[6+u]*inv; u++;
      e2 += (c == cp) ? w[c]*w[c]*mm : 2.0*w[c]*w[cp]*mm;
    }
  }
  double var = e2 - m*m;
  double a = (double)g1[o] / sqrt(var + 1e-5);
  #pragma unroll
  for (int c = 0; c < 6; c++) A1C1[c*64+o] = (float)(a*w[c]);
  A1C1[384+o] = (float)((double)b1[o] - a*m);
}

// ---------------- K4: conv1+bn1+relu+conv2 via MFMA bf16; k-pool + bn2 partials ----------------
// grid (128, 16), block 256 (4 waves). 16 n per block, k padded 20->32 with
// duplicates of neighbor 0 (max/min-invariant; sums mask pads).
__global__ __launch_bounds__(256) void k_conv12(const float* __restrict__ pc,
      const int* __restrict__ idxg, const float* __restrict__ A1C1,
      const float* __restrict__ W2,
      float* __restrict__ PS2, float* __restrict__ PQ2,
      short* __restrict__ P2MAX, short* __restrict__ P2MIN){
  __shared__ float es[6][512];         // 12 KB
  __shared__ short h1s[512*64];        // 64 KB, bf16, chunk-XOR swizzled
  __shared__ float w1s[448];
  __shared__ float ssum[128], ssq[128];
  const int tid = threadIdx.x;
  const int b = blockIdx.y;
  const int n0 = blockIdx.x*16;
  const float* pcb = pc + b*3*Nn;

  if (tid < 448) w1s[tid] = A1C1[tid];

  // edge gather (padded)
  for (int s = tid; s < 512; s += 256){
    int nl = s >> 5, kk = s & 31;
    int n = n0 + nl;
    int kke = (kk < 20) ? kk : 0;
    int m = idxg[((size_t)((b<<11)+n))*20 + kke];
    float cx = pcb[n],  cy = pcb[Nn+n],  cz = pcb[2*Nn+n];
    float px = pcb[m],  py = pcb[Nn+m],  pz = pcb[2*Nn+m];
    es[0][s] = cx;    es[1][s] = cy;    es[2][s] = cz;
    es[3][s] = px-cx; es[4][s] = py-cy; es[5][s] = pz-cz;
  }
  __syncthreads();

  // h1 = relu(W1f e + c1f) -> bf16 LDS [512][64], 16B-chunk XOR (s&7)
  for (int i = tid; i < 4096; i += 256){
    int s = i >> 3, oc = i & 7;
    bf16x8 hv;
    #pragma unroll
    for (int j = 0; j < 8; j++){
      int o = oc*8 + j;
      float acc = w1s[384 + o];
      #pragma unroll
      for (int c = 0; c < 6; c++) acc = fmaf(w1s[c*64 + o], es[c][s], acc);
      hv[j] = f2bf(fmaxf(acc, 0.f));
    }
    *(bf16x8*)&h1s[s*64 + ((oc ^ (s & 7)) << 3)] = hv;
  }
  __syncthreads();

  const int l = tid & 63, wv = tid >> 6;
  const int col = l & 15, kc = l >> 4;

  // B frags: W2[64 K][128 N], wave covers 32 cols
  bf16x8 Bf[2][2];
  #pragma unroll
  for (int qt = 0; qt < 2; qt++){
    int q = wv*32 + qt*16 + col;
    #pragma unroll
    for (int ks = 0; ks < 2; ks++){
      int k0 = ks*32 + kc*8;
      #pragma unroll
      for (int j = 0; j < 8; j++) Bf[qt][ks][j] = f2bf(W2[(k0+j)*128 + q]);
    }
  }

  float smacc[2] = {0.f, 0.f}, sqacc[2] = {0.f, 0.f};
  const bool t1real = (kc == 0);       // tile1 rows 16..19 real only in kc==0

  #pragma unroll 1
  for (int g = 0; g < 16; g++){
    bf16x8 Af[2][2];
    #pragma unroll
    for (int t = 0; t < 2; t++){
      int row = g*32 + t*16 + col;
      #pragma unroll
      for (int ks = 0; ks < 2; ks++){
        int chunk = (ks*4 + kc) ^ (row & 7);
        Af[t][ks] = *(const bf16x8*)&h1s[row*64 + chunk*8];
      }
    }
    #pragma unroll
    for (int qt = 0; qt < 2; qt++){
      f32x4 a0 = {0.f,0.f,0.f,0.f}, a1 = {0.f,0.f,0.f,0.f};
      a0 = __builtin_amdgcn_mfma_f32_16x16x32_bf16(Af[0][0], Bf[qt][0], a0, 0,0,0);
      a0 = __builtin_amdgcn_mfma_f32_16x16x32_bf16(Af[0][1], Bf[qt][1], a0, 0,0,0);
      a1 = __builtin_amdgcn_mfma_f32_16x16x32_bf16(Af[1][0], Bf[qt][0], a1, 0,0,0);
      a1 = __builtin_amdgcn_mfma_f32_16x16x32_bf16(Af[1][1], Bf[qt][1], a1, 0,0,0);
      float mx = a0[0], mn = a0[0], sm = 0.f, sq = 0.f;
      #pragma unroll
      for (int r = 0; r < 4; r++){
        float v0 = a0[r], v1 = a1[r];
        mx = fmaxf(mx, fmaxf(v0, v1));
        mn = fminf(mn, fminf(v0, v1));
        sm += v0; sq += v0*v0;
      }
      if (t1real){
        #pragma unroll
        for (int r = 0; r < 4; r++){ float v1 = a1[r]; sm += v1; sq += v1*v1; }
      }
      smacc[qt] += sm; sqacc[qt] += sq;
      mx = fmaxf(mx, __shfl_xor(mx, 16)); mx = fmaxf(mx, __shfl_xor(mx, 32));
      mn = fminf(mn, __shfl_xor(mn, 16)); mn = fminf(mn, __shfl_xor(mn, 32));
      if (kc == 0){
        size_t base = ((size_t)(b*Nn + n0 + g))*128 + (size_t)(wv*32 + qt*16 + col);
        P2MAX[base] = f2bf(mx);
        P2MIN[base] = f2bf(mn);
      }
    }
  }
  #pragma unroll
  for (int qt = 0; qt < 2; qt++){
    smacc[qt] += __shfl_xor(smacc[qt], 16); smacc[qt] += __shfl_xor(smacc[qt], 32);
    sqacc[qt] += __shfl_xor(sqacc[qt], 16); sqacc[qt] += __shfl_xor(sqacc[qt], 32);
    if (kc == 0){
      ssum[wv*32 + qt*16 + col] = smacc[qt];
      ssq [wv*32 + qt*16 + col] = sqacc[qt];
    }
  }
  __syncthreads();
  if (tid < 128){
    int bid = b*128 + blockIdx.x;
    PS2[tid*2048 + bid] = ssum[tid];
    PQ2[tid*2048 + bid] = ssq[tid];
  }
}

// ---------------- K5: bn2 affine from partial buffers ----------------
__global__ __launch_bounds__(256) void k_coef2(const float* __restrict__ PS2,
        const float* __restrict__ PQ2, const float* __restrict__ g2,
        const float* __restrict__ b2, float* __restrict__ A2C2){
  __shared__ float sred[4], qred[4];
  const int p = blockIdx.x;            // 128 blocks
  const int tid = threadIdx.x;
  float s = 0.f, q = 0.f;
  for (int i = tid; i < 2048; i += 256){ s += PS2[p*2048 + i]; q += PQ2[p*2048 + i]; }
  #pragma unroll
  for (int off = 32; off > 0; off >>= 1){ s += __shfl_xor(s, off); q += __shfl_xor(q, off); }
  if ((tid & 63) == 0){ sred[tid >> 6] = s; qred[tid >> 6] = q; }
  __syncthreads();
  if (tid == 0){
    double sum = (double)sred[0] + sred[1] + sred[2] + sred[3];
    double sq  = (double)qred[0] + qred[1] + qred[2] + qred[3];
    double mean = sum * (1.0/655360.0);
    double var  = sq  * (1.0/655360.0) - mean*mean;
    double a = (double)g2[p] / sqrt(var + 1e-5);
    A2C2[p]     = (float)a;
    A2C2[128+p] = (float)((double)b2[p] - a*mean);
  }
}

// ---------------- K6: bn2+relu + conv3 via MFMA bf16; bn3 stats + n-pool ----------------
__global__ __launch_bounds__(256) void k_conv3(const short* __restrict__ P2MAX,
      const short* __restrict__ P2MIN, const float* __restrict__ A2C2,
      const float* __restrict__ W3, double* __restrict__ S3SUM,
      double* __restrict__ S3SQ, unsigned* __restrict__ P3MAX,
      unsigned* __restrict__ P3MIN){
  __shared__ short As[128*128];        // bf16, chunk-XOR swizzled
  __shared__ float a2[128], c2[128];
  const int tid = threadIdx.x;
  const int b = blockIdx.y;
  const int n0 = blockIdx.x*128;
  const int qh = blockIdx.z;
  if (tid < 128){ a2[tid] = A2C2[tid]; c2[tid] = A2C2[128+tid]; }
  __syncthreads();

  for (int idx = tid; idx < 2048; idx += 256){
    int s = idx >> 4, oc = idx & 15;
    size_t base = ((size_t)(b*Nn + n0 + s))*128 + (size_t)(oc*8);
    bf16x8 vmx = *(const bf16x8*)&P2MAX[base];
    bf16x8 vmn = *(const bf16x8*)&P2MIN[base];
    bf16x8 vv;
    #pragma unroll
    for (int j = 0; j < 8; j++){
      int o = oc*8 + j;
      float aa = a2[o];
      float vsel = bf2f((aa >= 0.f) ? vmx[j] : vmn[j]);
      vv[j] = f2bf(fmaxf(aa*vsel + c2[o], 0.f));
    }
    int chunk = oc ^ (s & 7);
    *(bf16x8*)&As[s*128 + chunk*8] = vv;
  }
  __syncthreads();

  const int l = tid & 63, wv = tid >> 6;
  const int col = l & 15, kc = l >> 4;

  #pragma unroll 1
  for (int pass = 0; pass < 2; ++pass){
    bf16x8 Bf[4][4];
    #pragma unroll
    for (int qt = 0; qt < 4; qt++){
      int q = qh*512 + wv*128 + pass*64 + qt*16 + col;
      #pragma unroll
      for (int ks = 0; ks < 4; ks++){
        int k0 = ks*32 + kc*8;
        #pragma unroll
        for (int j = 0; j < 8; j++)
          Bf[qt][ks][j] = f2bf(W3[(size_t)(k0+j)*1024 + q]);
      }
    }
    float smx[4], smn[4], ssm[4], ssqv[4];
    #pragma unroll
    for (int qt = 0; qt < 4; qt++){ smx[qt] = -3.4e38f; smn[qt] = 3.4e38f; ssm[qt] = 0.f; ssqv[qt] = 0.f; }

    #pragma unroll 1
    for (int st = 0; st < 8; ++st){
      bf16x8 Af[4];
      int row = st*16 + col;
      #pragma unroll
      for (int ks = 0; ks < 4; ks++){
        int chunk = (ks*4 + kc) ^ (row & 7);
        Af[ks] = *(const bf16x8*)&As[row*128 + chunk*8];
      }
      #pragma unroll
      for (int qt = 0; qt < 4; qt++){
        f32x4 acc = {0.f, 0.f, 0.f, 0.f};
        #pragma unroll
        for (int ks = 0; ks < 4; ks++)
          acc = __builtin_amdgcn_mfma_f32_16x16x32_bf16(Af[ks], Bf[qt][ks], acc, 0, 0, 0);
        #pragma unroll
        for (int r = 0; r < 4; r++){
          float vv = acc[r];
          smx[qt] = fmaxf(smx[qt], vv); smn[qt] = fminf(smn[qt], vv);
          ssm[qt] += vv; ssqv[qt] += vv*vv;
        }
      }
    }
    #pragma unroll
    for (int qt = 0; qt < 4; qt++){
      #pragma unroll
      for (int off = 16; off <= 32; off <<= 1){
        smx[qt] = fmaxf(smx[qt], __shfl_xor(smx[qt], off));
        smn[qt] = fminf(smn[qt], __shfl_xor(smn[qt], off));
        ssm[qt] += __shfl_xor(ssm[qt], off);
        ssqv[qt] += __shfl_xor(ssqv[qt], off);
      }
    }
    if (kc == 0){
      #pragma unroll
      for (int qt = 0; qt < 4; qt++){
        int q = qh*512 + wv*128 + pass*64 + qt*16 + col;
        atomicMax(&P3MAX[b*1024 + q], fkey(smx[qt]));
        atomicMin(&P3MIN[b*1024 + q], fkey(smn[qt]));
        atomicAdd(&S3SUM[q], (double)ssm[qt]);
        atomicAdd(&S3SQ[q],  (double)ssqv[qt]);
      }
    }
  }
}

// ---------------- K7: bn3+relu on pooled values ----------------
__global__ __launch_bounds__(256) void k_bn3relu(const double* __restrict__ S3SUM,
      const double* __restrict__ S3SQ, const unsigned* __restrict__ P3MAX,
      const unsigned* __restrict__ P3MIN, const float* __restrict__ g3,
      const float* __restrict__ b3, float* __restrict__ R3){
  int id = blockIdx.x*256 + threadIdx.x;          // 16384
  int q = id & 1023;
  double mean = S3SUM[q] * (1.0/32768.0);
  double var  = S3SQ[q] * (1.0/32768.0) - mean*mean;
  double a = (double)g3[q] / sqrt(var + 1e-5);
  double c = (double)b3[q] - a*mean;
  float v = fdec((a >= 0.0) ? P3MAX[id] : P3MIN[id]);
  R3[id] = fmaxf((float)(a*(double)v + c), 0.f);
}

// ---------------- FC: partial dots (coalesced W) + BN ----------------
template<int IN, int OUT>
__global__ __launch_bounds__(256) void k_fcdot(const float* __restrict__ X,
      const float* __restrict__ W, float* __restrict__ dots){
  constexpr int L = IN/16;
  __shared__ float Xs[16*L];
  const int tid = threadIdx.x;
  const int o = blockIdx.x*64 + (tid & 63);
  const int wv = tid >> 6;
  const int c0 = blockIdx.y*L;
  for (int i = tid; i < 16*L; i += 256){
    int bb = i / L, cc = i - bb*L;
    Xs[i] = X[bb*IN + c0 + cc];
  }
  __syncthreads();
  constexpr int CPW = L/4;
  float acc[16];
  #pragma unroll
  for (int bb = 0; bb < 16; bb++) acc[bb] = 0.f;
  for (int cc = wv*CPW; cc < (wv+1)*CPW; ++cc){
    float w = W[(size_t)(c0+cc)*OUT + o];
    #pragma unroll
    for (int bb = 0; bb < 16; bb++) acc[bb] += Xs[bb*L + cc]*w;
  }
  #pragma unroll
  for (int bb = 0; bb < 16; bb++) atomicAdd(&dots[bb*OUT + o], acc[bb]);
}

template<int OUT>
__global__ __launch_bounds__(64) void k_fcbn(const float* __restrict__ dots,
      const float* __restrict__ g, const float* __restrict__ bet,
      float* __restrict__ Y){
  const int o = blockIdx.x*64 + threadIdx.x;
  float d[16]; float m = 0.f;
  #pragma unroll
  for (int bb = 0; bb < 16; bb++){ d[bb] = dots[bb*OUT + o]; m += d[bb]; }
  m *= (1.f/16.f);
  float v = 0.f;
  #pragma unroll
  for (int bb = 0; bb < 16; bb++){ float x = d[bb]-m; v += x*x; }
  v *= (1.f/16.f);
  float a = g[o] * rsqrtf(v + 1e-5f);
  #pragma unroll
  for (int bb = 0; bb < 16; bb++) Y[bb*OUT + o] = fmaxf(a*(d[bb]-m) + bet[o], 0.f);
}

// ---------------- K10: final 256->9 + bias ----------------
__global__ __launch_bounds__(192) void k_head(const float* __restrict__ R5,
      const float* __restrict__ Wf3, const float* __restrict__ bf3,
      float* __restrict__ out){
  int t = threadIdx.x;
  if (t >= 144) return;
  int b = t/9, j = t - b*9;
  float acc = bf3[j];
  for (int c = 0; c < 256; c++) acc += R5[b*256 + c]*Wf3[c*9 + j];
  out[t] = acc;
}

extern "C" void kernel_launch(void* const* d_in, const int* in_sizes, int n_in,
                              void* d_out, int out_size, void* d_ws, size_t ws_size,
                              hipStream_t stream) {
  if (ws_size < WS_NEEDED) return;
  const float* pc  = (const float*)d_in[0];
  const float* W1  = (const float*)d_in[1];
  const float* g1  = (const float*)d_in[2];
  const float* b1  = (const float*)d_in[3];
  const float* W2  = (const float*)d_in[4];
  const float* g2  = (const float*)d_in[5];
  const float* b2  = (const float*)d_in[6];
  const float* W3  = (const float*)d_in[7];
  const float* g3  = (const float*)d_in[8];
  const float* b3  = (const float*)d_in[9];
  const float* Wf1 = (const float*)d_in[10];
  const float* gf1 = (const float*)d_in[11];
  const float* bf1 = (const float*)d_in[12];
  const float* Wf2 = (const float*)d_in[13];
  const float* gf2 = (const float*)d_in[14];
  const float* bf2 = (const float*)d_in[15];
  const float* Wf3 = (const float*)d_in[16];
  const float* bf3 = (const float*)d_in[17];

  char* ws = (char*)d_ws;
  int*      IDX   = (int*)     (ws + OFF_IDX);
  short*    P2MAXp= (short*)   (ws + OFF_P2MAX);
  short*    P2MINp= (short*)   (ws + OFF_P2MIN);
  float*    PS2p  = (float*)   (ws + OFF_PS2);
  float*    PQ2p  = (float*)   (ws + OFF_PQ2);
  double*   MOMp  = (double*)  (ws + OFF_MOM);
  float*    A1C1p = (float*)   (ws + OFF_A1C1);
  float*    A2C2p = (float*)   (ws + OFF_A2C2);
  double*   S3SUMp= (double*)  (ws + OFF_S3SUM);
  double*   S3SQp = (double*)  (ws + OFF_S3SQ);
  unsigned* P3MAXp= (unsigned*)(ws + OFF_P3MAX);
  unsigned* P3MINp= (unsigned*)(ws + OFF_P3MIN);
  float*    R3p   = (float*)   (ws + OFF_R3);
  float*    R4p   = (float*)   (ws + OFF_R4);
  float*    R5p   = (float*)   (ws + OFF_R5);
  float*    DOTS1p= (float*)   (ws + OFF_DOTS1);
  float*    DOTS2p= (float*)   (ws + OFF_DOTS2);

  k_init          <<<dim3(64),       256, 0, stream>>>(ws);
  k_knn           <<<dim3(32,16),    256, 0, stream>>>(pc, IDX, MOMp);
  k_coef1         <<<dim3(1),         64, 0, stream>>>(MOMp, W1, g1, b1, A1C1p);
  k_conv12        <<<dim3(128,16),   256, 0, stream>>>(pc, IDX, A1C1p, W2, PS2p, PQ2p, P2MAXp, P2MINp);
  k_coef2         <<<dim3(128),      256, 0, stream>>>(PS2p, PQ2p, g2, b2, A2C2p);
  k_conv3         <<<dim3(16,16,2),  256, 0, stream>>>(P2MAXp, P2MINp, A2C2p, W3, S3SUMp, S3SQp, P3MAXp, P3MINp);
  k_bn3relu       <<<dim3(64),       256, 0, stream>>>(S3SUMp, S3SQp, P3MAXp, P3MINp, g3, b3, R3p);
  k_fcdot<1024,512><<<dim3(8,16),    256, 0, stream>>>(R3p, Wf1, DOTS1p);
  k_fcbn<512>     <<<dim3(8),         64, 0, stream>>>(DOTS1p, gf1, bf1, R4p);
  k_fcdot<512,256><<<dim3(4,16),     256, 0, stream>>>(R4p, Wf2, DOTS2p);
  k_fcbn<256>     <<<dim3(4),         64, 0, stream>>>(DOTS2p, gf2, bf2, R5p);
  k_head          <<<dim3(1),        192, 0, stream>>>(R5p, Wf3, bf3, (float*)d_out);
}

// Round 6
// 236.256 us; speedup vs baseline: 4.7456x; 1.2485x over previous
//
#include <hip/hip_runtime.h>
#include <math.h>

#define Nn 2048

// ---------------- workspace layout (bytes) ----------------
#define OFF_IDX    ((size_t)0)                    // 16*2048*20*4 = 2.62 MB
#define OFF_P2MAX  (((size_t)4)  << 20)           // 16*2048*128*2 = 8.39 MB (bf16)
#define OFF_P2MIN  (((size_t)13) << 20)           // 8.39 MB (bf16)
#define OFF_PS2    (((size_t)22) << 20)           // 128*2048 float = 1 MB
#define OFF_PQ2    (((size_t)23) << 20)           // 1 MB
#define OFF_STATS  (((size_t)24) << 20)
#define OFF_MOM    (OFF_STATS + 0)                // 27 double
#define OFF_A1C1   (OFF_STATS + 4096)             // 448 float (folded W1 + bias)
#define OFF_A2C2   (OFF_STATS + 8192)             // 256 float
#define OFF_S3SUM  (OFF_STATS + 12288)            // 1024 double
#define OFF_S3SQ   (OFF_STATS + 20480)            // 1024 double
#define OFF_P3MAX  (OFF_STATS + 28672)            // 16*1024 uint
#define OFF_P3MIN  (OFF_STATS + 94208)            // 16*1024 uint
#define OFF_R3     (OFF_STATS + 159744)           // 16*1024 float
#define OFF_R4     (OFF_STATS + 225280)           // 16*512 float
#define OFF_R5     (OFF_STATS + 258048)           // 16*256 float
#define OFF_DOTS1  (OFF_STATS + 274432)           // 16*512 float
#define OFF_DOTS2  (OFF_STATS + 307200)           // 16*256 float
#define WS_NEEDED  (OFF_STATS + 323584)

typedef __attribute__((ext_vector_type(8))) short bf16x8;
typedef __attribute__((ext_vector_type(4))) float f32x4;

__device__ __forceinline__ unsigned fkey(float f){
  unsigned u = __float_as_uint(f);
  return (u & 0x80000000u) ? ~u : (u | 0x80000000u);
}
__device__ __forceinline__ float fdec(unsigned k){
  unsigned u = (k & 0x80000000u) ? (k & 0x7FFFFFFFu) : ~k;
  return __uint_as_float(u);
}
__device__ __forceinline__ short f2bf(float x){
  unsigned u = __float_as_uint(x);
  u += 0x7fffu + ((u >> 16) & 1u);                // RNE
  return (short)(u >> 16);
}
__device__ __forceinline__ float bf2f(short v){
  return __uint_as_float(((unsigned)(unsigned short)v) << 16);
}
__device__ __forceinline__ float med3(float a, float b, float c){
  float d;
  asm("v_med3_f32 %0, %1, %2, %3" : "=v"(d) : "v"(a), "v"(b), "v"(c));
  return d;
}
// Explicit fmaf chain: bit-identical codegen wherever it is inlined (the
// compiler may NOT re-contract explicit fmaf), so pass-1 values == pass-2
// values exactly, guaranteeing the threshold test re-selects >= 20 items.
__device__ __forceinline__ float ndist(float tQx, float tQy, float tQz, float Qw, float4 P){
  return fmaf(tQx, P.x, fmaf(tQy, P.y, fmaf(tQz, P.z, -Qw - P.w)));
}
// branch-free insert of x into ascending sorted top-20
__device__ __forceinline__ void insert20(float (&m)[20], float x){
  #pragma unroll
  for (int t = 0; t < 19; t++) m[t] = med3(m[t], m[t+1], x);
  m[19] = fmaxf(m[19], x);
}

// ---------------- K0: per-launch accumulator init ----------------
__global__ __launch_bounds__(256) void k_init(char* __restrict__ ws){
  int i = blockIdx.x*256 + threadIdx.x;
  if (i < 7168) ((unsigned*)(ws + OFF_MOM))[i] = 0u;       // MOM..S3SQ (28,672 B)
  if (i < 16384){
    ((unsigned*)(ws + OFF_P3MAX))[i] = 0u;
    ((unsigned*)(ws + OFF_P3MIN))[i] = 0xFFFFFFFFu;
  }
  if (i < 12288) ((float*)(ws + OFF_DOTS1))[i] = 0.f;      // DOTS1+DOTS2
}

// ---------------- K1: KNN top-20 ----------------
// grid (64,16), block 256. 8 threads/query x 256 candidates; sorted-20 via
// med3; register-only shfl-butterfly merge (8 lanes/query within one wave);
// moments recomputed from the final index sets.
__global__ __launch_bounds__(256) void k_knn(const float* __restrict__ pc,
                                             int* __restrict__ idxg,
                                             double* __restrict__ MOM){
  __shared__ float4 pts[Nn];           // 32 KB
  __shared__ unsigned cnt[32];
  __shared__ float momS[27];
  const int tid = threadIdx.x;
  const int b = blockIdx.y;
  const int n0 = blockIdx.x*32;
  const float* pcb = pc + b*3*Nn;
  for (int i = tid; i < Nn; i += 256){
    float x = pcb[i], y = pcb[Nn+i], z = pcb[2*Nn+i];
    pts[i] = make_float4(x, y, z, x*x + y*y + z*z);
  }
  if (tid < 32) cnt[tid] = 0u;
  if (tid < 27) momS[tid] = 0.f;
  __syncthreads();

  const int ql = tid >> 3, c = tid & 7;
  const int n = n0 + ql;
  const float4 Q = pts[n];
  const float tQx = 2.f*Q.x, tQy = 2.f*Q.y, tQz = 2.f*Q.z;

  // pass 1: per-thread sorted top-20 of its 256 candidates (loads batched x4)
  float v[20];
  #pragma unroll
  for (int t = 0; t < 20; t++) v[t] = -3.4e38f;
  #pragma unroll 1
  for (int i = 0; i < 256; i += 4){
    float4 P0 = pts[(i+0)*8 + c];
    float4 P1 = pts[(i+1)*8 + c];
    float4 P2 = pts[(i+2)*8 + c];
    float4 P3 = pts[(i+3)*8 + c];
    insert20(v, ndist(tQx, tQy, tQz, Q.w, P0));
    insert20(v, ndist(tQx, tQy, tQz, Q.w, P1));
    insert20(v, ndist(tQx, tQy, tQz, Q.w, P2));
    insert20(v, ndist(tQx, tQy, tQz, Q.w, P3));
  }

  // register-only symmetric butterfly merge across the 8 lanes of this query.
  // After stages xor {4,2,1} every lane holds top-20 of all 2048 candidates.
  #pragma unroll
  for (int stage = 4; stage >= 1; stage >>= 1){
    float w[20];
    #pragma unroll
    for (int t = 0; t < 20; t++) w[t] = __shfl_xor(v[t], stage);
    #pragma unroll
    for (int t = 0; t < 20; t++) insert20(v, w[t]);
  }
  const float th = v[0];               // exact 20th-largest of all 2048

  // pass 2: emit indices with nd >= th (tiny branch body)
  int* myidx = &idxg[((size_t)((b<<11) + n))*20];
  #pragma unroll 1
  for (int i = 0; i < 256; i += 4){
    float4 P0 = pts[(i+0)*8 + c];
    float4 P1 = pts[(i+1)*8 + c];
    float4 P2 = pts[(i+2)*8 + c];
    float4 P3 = pts[(i+3)*8 + c];
    float nd0 = ndist(tQx, tQy, tQz, Q.w, P0);
    float nd1 = ndist(tQx, tQy, tQz, Q.w, P1);
    float nd2 = ndist(tQx, tQy, tQz, Q.w, P2);
    float nd3 = ndist(tQx, tQy, tQz, Q.w, P3);
    if (nd0 >= th){ unsigned p = atomicAdd(&cnt[ql], 1u); if (p < 20u) myidx[p] = (i+0)*8 + c; }
    if (nd1 >= th){ unsigned p = atomicAdd(&cnt[ql], 1u); if (p < 20u) myidx[p] = (i+1)*8 + c; }
    if (nd2 >= th){ unsigned p = atomicAdd(&cnt[ql], 1u); if (p < 20u) myidx[p] = (i+2)*8 + c; }
    if (nd3 >= th){ unsigned p = atomicAdd(&cnt[ql], 1u); if (p < 20u) myidx[p] = (i+3)*8 + c; }
  }
  __threadfence_block();
  __syncthreads();                     // idxg + cnt visible block-wide

  // safety net: guarantee all 20 slots are initialized (self-index filler).
  // With the exact fmaf recompute this never triggers; it exists so that a
  // pathological FP mismatch can never produce wild gather addresses.
  if (c == 0){
    unsigned have = cnt[ql]; if (have > 20u) have = 20u;
    for (unsigned p = have; p < 20u; ++p) myidx[p] = n;
  }
  __threadfence_block();
  __syncthreads();

  // edge moments from the exact selected sets: 32 q x 20 = 640 edges
  float s1[6] = {0,0,0,0,0,0};
  float s2[21] = {0,0,0,0,0,0,0,0,0,0,0,0,0,0,0,0,0,0,0,0,0};
  #pragma unroll 1
  for (int j = tid; j < 640; j += 256){
    int q = j/20, t = j - q*20;
    int m = idxg[((size_t)((b<<11) + n0 + q))*20 + t] & 2047;
    float4 P = pts[m];
    float4 Qq = pts[n0 + q];
    float e[6] = {Qq.x, Qq.y, Qq.z, P.x - Qq.x, P.y - Qq.y, P.z - Qq.z};
    int u = 0;
    #pragma unroll
    for (int a = 0; a < 6; a++){
      s1[a] += e[a];
      #pragma unroll
      for (int bq = a; bq < 6; bq++){ s2[u] += e[a]*e[bq]; u++; }
    }
  }
  #pragma unroll
  for (int a = 0; a < 6; a++)
    for (int off = 32; off > 0; off >>= 1) s1[a] += __shfl_xor(s1[a], off);
  #pragma unroll
  for (int u = 0; u < 21; u++)
    for (int off = 32; off > 0; off >>= 1) s2[u] += __shfl_xor(s2[u], off);
  if ((tid & 63) == 0){
    #pragma unroll
    for (int a = 0; a < 6; a++) atomicAdd(&momS[a], s1[a]);
    #pragma unroll
    for (int u = 0; u < 21; u++) atomicAdd(&momS[6+u], s2[u]);
  }
  __syncthreads();
  if (tid < 27) atomicAdd(&MOM[tid], (double)momS[tid]);
}

// ---------------- K3: bn1 affine folded into W1 ----------------
// A1C1 out: [0..383] = a1[o]*W1[c][o] (c-major), [384..447] = c1 bias
__global__ __launch_bounds__(64) void k_coef1(const double* __restrict__ MOM,
        const float* __restrict__ W1, const float* __restrict__ g1,
        const float* __restrict__ b1, float* __restrict__ A1C1){
  const int o = threadIdx.x;
  const double inv = 1.0/655360.0;
  double w[6]; double m = 0.0;
  #pragma unroll
  for (int c = 0; c < 6; c++){ w[c] = (double)W1[c*64+o]; m += w[c]*MOM[c]*inv; }
  double e2 = 0.0; int u = 0;
  #pragma unroll
  for (int c = 0; c < 6; c++){
    #pragma unroll
    for (int cp = c; cp < 6; cp++){
      double mm = MOM[6+u]*inv; u++;
      e2 += (c == cp) ? w[c]*w[c]*mm : 2.0*w[c]*w[cp]*mm;
    }
  }
  double var = e2 - m*m;
  double a = (double)g1[o] / sqrt(var + 1e-5);
  #pragma unroll
  for (int c = 0; c < 6; c++) A1C1[c*64+o] = (float)(a*w[c]);
  A1C1[384+o] = (float)((double)b1[o] - a*m);
}

// ---------------- K4: conv1+bn1+relu+conv2 via MFMA bf16; k-pool + bn2 partials ----------------
__global__ __launch_bounds__(256) void k_conv12(const float* __restrict__ pc,
      const int* __restrict__ idxg, const float* __restrict__ A1C1,
      const float* __restrict__ W2,
      float* __restrict__ PS2, float* __restrict__ PQ2,
      short* __restrict__ P2MAX, short* __restrict__ P2MIN){
  __shared__ float es[6][512];         // 12 KB
  __shared__ short h1s[512*64];        // 64 KB, bf16, chunk-XOR swizzled
  __shared__ float w1s[448];
  __shared__ float ssum[128], ssq[128];
  const int tid = threadIdx.x;
  const int b = blockIdx.y;
  const int n0 = blockIdx.x*16;
  const float* pcb = pc + b*3*Nn;

  for (int i = tid; i < 448; i += 256) w1s[i] = A1C1[i];

  for (int s = tid; s < 512; s += 256){
    int nl = s >> 5, kk = s & 31;
    int n = n0 + nl;
    int kke = (kk < 20) ? kk : 0;
    int m = idxg[((size_t)((b<<11)+n))*20 + kke] & 2047;   // clamp: no wild gathers
    float cx = pcb[n],  cy = pcb[Nn+n],  cz = pcb[2*Nn+n];
    float px = pcb[m],  py = pcb[Nn+m],  pz = pcb[2*Nn+m];
    es[0][s] = cx;    es[1][s] = cy;    es[2][s] = cz;
    es[3][s] = px-cx; es[4][s] = py-cy; es[5][s] = pz-cz;
  }
  __syncthreads();

  for (int i = tid; i < 4096; i += 256){
    int s = i >> 3, oc = i & 7;
    bf16x8 hv;
    #pragma unroll
    for (int j = 0; j < 8; j++){
      int o = oc*8 + j;
      float acc = w1s[384 + o];
      #pragma unroll
      for (int c = 0; c < 6; c++) acc = fmaf(w1s[c*64 + o], es[c][s], acc);
      hv[j] = f2bf(fmaxf(acc, 0.f));
    }
    *(bf16x8*)&h1s[s*64 + ((oc ^ (s & 7)) << 3)] = hv;
  }
  __syncthreads();

  const int l = tid & 63, wv = tid >> 6;
  const int col = l & 15, kc = l >> 4;

  bf16x8 Bf[2][2];
  #pragma unroll
  for (int qt = 0; qt < 2; qt++){
    int q = wv*32 + qt*16 + col;
    #pragma unroll
    for (int ks = 0; ks < 2; ks++){
      int k0 = ks*32 + kc*8;
      #pragma unroll
      for (int j = 0; j < 8; j++) Bf[qt][ks][j] = f2bf(W2[(k0+j)*128 + q]);
    }
  }

  float smacc[2] = {0.f, 0.f}, sqacc[2] = {0.f, 0.f};
  const bool t1real = (kc == 0);

  #pragma unroll 1
  for (int g = 0; g < 16; g++){
    bf16x8 Af[2][2];
    #pragma unroll
    for (int t = 0; t < 2; t++){
      int row = g*32 + t*16 + col;
      #pragma unroll
      for (int ks = 0; ks < 2; ks++){
        int chunk = (ks*4 + kc) ^ (row & 7);
        Af[t][ks] = *(const bf16x8*)&h1s[row*64 + chunk*8];
      }
    }
    #pragma unroll
    for (int qt = 0; qt < 2; qt++){
      f32x4 a0 = {0.f,0.f,0.f,0.f}, a1 = {0.f,0.f,0.f,0.f};
      a0 = __builtin_amdgcn_mfma_f32_16x16x32_bf16(Af[0][0], Bf[qt][0], a0, 0,0,0);
      a0 = __builtin_amdgcn_mfma_f32_16x16x32_bf16(Af[0][1], Bf[qt][1], a0, 0,0,0);
      a1 = __builtin_amdgcn_mfma_f32_16x16x32_bf16(Af[1][0], Bf[qt][0], a1, 0,0,0);
      a1 = __builtin_amdgcn_mfma_f32_16x16x32_bf16(Af[1][1], Bf[qt][1], a1, 0,0,0);
      float mx = a0[0], mn = a0[0], sm = 0.f, sq = 0.f;
      #pragma unroll
      for (int r = 0; r < 4; r++){
        float v0 = a0[r], v1 = a1[r];
        mx = fmaxf(mx, fmaxf(v0, v1));
        mn = fminf(mn, fminf(v0, v1));
        sm += v0; sq += v0*v0;
      }
      if (t1real){
        #pragma unroll
        for (int r = 0; r < 4; r++){ float v1 = a1[r]; sm += v1; sq += v1*v1; }
      }
      smacc[qt] += sm; sqacc[qt] += sq;
      mx = fmaxf(mx, __shfl_xor(mx, 16)); mx = fmaxf(mx, __shfl_xor(mx, 32));
      mn = fminf(mn, __shfl_xor(mn, 16)); mn = fminf(mn, __shfl_xor(mn, 32));
      if (kc == 0){
        size_t base = ((size_t)(b*Nn + n0 + g))*128 + (size_t)(wv*32 + qt*16 + col);
        P2MAX[base] = f2bf(mx);
        P2MIN[base] = f2bf(mn);
      }
    }
  }
  #pragma unroll
  for (int qt = 0; qt < 2; qt++){
    smacc[qt] += __shfl_xor(smacc[qt], 16); smacc[qt] += __shfl_xor(smacc[qt], 32);
    sqacc[qt] += __shfl_xor(sqacc[qt], 16); sqacc[qt] += __shfl_xor(sqacc[qt], 32);
    if (kc == 0){
      ssum[wv*32 + qt*16 + col] = smacc[qt];
      ssq [wv*32 + qt*16 + col] = sqacc[qt];
    }
  }
  __syncthreads();
  if (tid < 128){
    int bid = b*128 + blockIdx.x;
    PS2[tid*2048 + bid] = ssum[tid];
    PQ2[tid*2048 + bid] = ssq[tid];
  }
}

// ---------------- K5: bn2 affine from partial buffers ----------------
__global__ __launch_bounds__(256) void k_coef2(const float* __restrict__ PS2,
        const float* __restrict__ PQ2, const float* __restrict__ g2,
        const float* __restrict__ b2, float* __restrict__ A2C2){
  __shared__ float sred[4], qred[4];
  const int p = blockIdx.x;
  const int tid = threadIdx.x;
  float s = 0.f, q = 0.f;
  for (int i = tid; i < 2048; i += 256){ s += PS2[p*2048 + i]; q += PQ2[p*2048 + i]; }
  #pragma unroll
  for (int off = 32; off > 0; off >>= 1){ s += __shfl_xor(s, off); q += __shfl_xor(q, off); }
  if ((tid & 63) == 0){ sred[tid >> 6] = s; qred[tid >> 6] = q; }
  __syncthreads();
  if (tid == 0){
    double sum = (double)sred[0] + sred[1] + sred[2] + sred[3];
    double sq  = (double)qred[0] + qred[1] + qred[2] + qred[3];
    double mean = sum * (1.0/655360.0);
    double var  = sq  * (1.0/655360.0) - mean*mean;
    double a = (double)g2[p] / sqrt(var + 1e-5);
    A2C2[p]     = (float)a;
    A2C2[128+p] = (float)((double)b2[p] - a*mean);
  }
}

// ---------------- K6: bn2+relu + conv3 via MFMA bf16; bn3 stats + n-pool ----------------
__global__ __launch_bounds__(256) void k_conv3(const short* __restrict__ P2MAX,
      const short* __restrict__ P2MIN, const float* __restrict__ A2C2,
      const float* __restrict__ W3, double* __restrict__ S3SUM,
      double* __restrict__ S3SQ, unsigned* __restrict__ P3MAX,
      unsigned* __restrict__ P3MIN){
  __shared__ short As[128*128];
  __shared__ float a2[128], c2[128];
  const int tid = threadIdx.x;
  const int b = blockIdx.y;
  const int n0 = blockIdx.x*128;
  const int qh = blockIdx.z;
  if (tid < 128){ a2[tid] = A2C2[tid]; c2[tid] = A2C2[128+tid]; }
  __syncthreads();

  for (int idx = tid; idx < 2048; idx += 256){
    int s = idx >> 4, oc = idx & 15;
    size_t base = ((size_t)(b*Nn + n0 + s))*128 + (size_t)(oc*8);
    bf16x8 vmx = *(const bf16x8*)&P2MAX[base];
    bf16x8 vmn = *(const bf16x8*)&P2MIN[base];
    bf16x8 vv;
    #pragma unroll
    for (int j = 0; j < 8; j++){
      int o = oc*8 + j;
      float aa = a2[o];
      float vsel = bf2f((aa >= 0.f) ? vmx[j] : vmn[j]);
      vv[j] = f2bf(fmaxf(aa*vsel + c2[o], 0.f));
    }
    int chunk = oc ^ (s & 7);
    *(bf16x8*)&As[s*128 + chunk*8] = vv;
  }
  __syncthreads();

  const int l = tid & 63, wv = tid >> 6;
  const int col = l & 15, kc = l >> 4;

  #pragma unroll 1
  for (int pass = 0; pass < 2; ++pass){
    bf16x8 Bf[4][4];
    #pragma unroll
    for (int qt = 0; qt < 4; qt++){
      int q = qh*512 + wv*128 + pass*64 + qt*16 + col;
      #pragma unroll
      for (int ks = 0; ks < 4; ks++){
        int k0 = ks*32 + kc*8;
        #pragma unroll
        for (int j = 0; j < 8; j++)
          Bf[qt][ks][j] = f2bf(W3[(size_t)(k0+j)*1024 + q]);
      }
    }
    float smx[4], smn[4], ssm[4], ssqv[4];
    #pragma unroll
    for (int qt = 0; qt < 4; qt++){ smx[qt] = -3.4e38f; smn[qt] = 3.4e38f; ssm[qt] = 0.f; ssqv[qt] = 0.f; }

    #pragma unroll 1
    for (int st = 0; st < 8; ++st){
      bf16x8 Af[4];
      int row = st*16 + col;
      #pragma unroll
      for (int ks = 0; ks < 4; ks++){
        int chunk = (ks*4 + kc) ^ (row & 7);
        Af[ks] = *(const bf16x8*)&As[row*128 + chunk*8];
      }
      #pragma unroll
      for (int qt = 0; qt < 4; qt++){
        f32x4 acc = {0.f, 0.f, 0.f, 0.f};
        #pragma unroll
        for (int ks = 0; ks < 4; ks++)
          acc = __builtin_amdgcn_mfma_f32_16x16x32_bf16(Af[ks], Bf[qt][ks], acc, 0, 0, 0);
        #pragma unroll
        for (int r = 0; r < 4; r++){
          float vv = acc[r];
          smx[qt] = fmaxf(smx[qt], vv); smn[qt] = fminf(smn[qt], vv);
          ssm[qt] += vv; ssqv[qt] += vv*vv;
        }
      }
    }
    #pragma unroll
    for (int qt = 0; qt < 4; qt++){
      #pragma unroll
      for (int off = 16; off <= 32; off <<= 1){
        smx[qt] = fmaxf(smx[qt], __shfl_xor(smx[qt], off));
        smn[qt] = fminf(smn[qt], __shfl_xor(smn[qt], off));
        ssm[qt] += __shfl_xor(ssm[qt], off);
        ssqv[qt] += __shfl_xor(ssqv[qt], off);
      }
    }
    if (kc == 0){
      #pragma unroll
      for (int qt = 0; qt < 4; qt++){
        int q = qh*512 + wv*128 + pass*64 + qt*16 + col;
        atomicMax(&P3MAX[b*1024 + q], fkey(smx[qt]));
        atomicMin(&P3MIN[b*1024 + q], fkey(smn[qt]));
        atomicAdd(&S3SUM[q], (double)ssm[qt]);
        atomicAdd(&S3SQ[q],  (double)ssqv[qt]);
      }
    }
  }
}

// ---------------- K7: bn3+relu on pooled values ----------------
__global__ __launch_bounds__(256) void k_bn3relu(const double* __restrict__ S3SUM,
      const double* __restrict__ S3SQ, const unsigned* __restrict__ P3MAX,
      const unsigned* __restrict__ P3MIN, const float* __restrict__ g3,
      const float* __restrict__ b3, float* __restrict__ R3){
  int id = blockIdx.x*256 + threadIdx.x;          // 16384
  int q = id & 1023;
  double mean = S3SUM[q] * (1.0/32768.0);
  double var  = S3SQ[q] * (1.0/32768.0) - mean*mean;
  double a = (double)g3[q] / sqrt(var + 1e-5);
  double c = (double)b3[q] - a*mean;
  float v = fdec((a >= 0.0) ? P3MAX[id] : P3MIN[id]);
  R3[id] = fmaxf((float)(a*(double)v + c), 0.f);
}

// ---------------- FC: partial dots (coalesced W) + BN ----------------
template<int IN, int OUT>
__global__ __launch_bounds__(256) void k_fcdot(const float* __restrict__ X,
      const float* __restrict__ W, float* __restrict__ dots){
  constexpr int L = IN/16;
  __shared__ float Xs[16*L];
  const int tid = threadIdx.x;
  const int o = blockIdx.x*64 + (tid & 63);
  const int wv = tid >> 6;
  const int c0 = blockIdx.y*L;
  for (int i = tid; i < 16*L; i += 256){
    int bb = i / L, cc = i - bb*L;
    Xs[i] = X[bb*IN + c0 + cc];
  }
  __syncthreads();
  constexpr int CPW = L/4;
  float acc[16];
  #pragma unroll
  for (int bb = 0; bb < 16; bb++) acc[bb] = 0.f;
  for (int cc = wv*CPW; cc < (wv+1)*CPW; ++cc){
    float w = W[(size_t)(c0+cc)*OUT + o];
    #pragma unroll
    for (int bb = 0; bb < 16; bb++) acc[bb] += Xs[bb*L + cc]*w;
  }
  #pragma unroll
  for (int bb = 0; bb < 16; bb++) atomicAdd(&dots[bb*OUT + o], acc[bb]);
}

template<int OUT>
__global__ __launch_bounds__(64) void k_fcbn(const float* __restrict__ dots,
      const float* __restrict__ g, const float* __restrict__ bet,
      float* __restrict__ Y){
  const int o = blockIdx.x*64 + threadIdx.x;
  float d[16]; float m = 0.f;
  #pragma unroll
  for (int bb = 0; bb < 16; bb++){ d[bb] = dots[bb*OUT + o]; m += d[bb]; }
  m *= (1.f/16.f);
  float v = 0.f;
  #pragma unroll
  for (int bb = 0; bb < 16; bb++){ float x = d[bb]-m; v += x*x; }
  v *= (1.f/16.f);
  float a = g[o] * rsqrtf(v + 1e-5f);
  #pragma unroll
  for (int bb = 0; bb < 16; bb++) Y[bb*OUT + o] = fmaxf(a*(d[bb]-m) + bet[o], 0.f);
}

// ---------------- K10: final 256->9 + bias ----------------
__global__ __launch_bounds__(192) void k_head(const float* __restrict__ R5,
      const float* __restrict__ Wf3, const float* __restrict__ bf3,
      float* __restrict__ out){
  int t = threadIdx.x;
  if (t >= 144) return;
  int b = t/9, j = t - b*9;
  float acc = bf3[j];
  for (int c = 0; c < 256; c++) acc += R5[b*256 + c]*Wf3[c*9 + j];
  out[t] = acc;
}

extern "C" void kernel_launch(void* const* d_in, const int* in_sizes, int n_in,
                              void* d_out, int out_size, void* d_ws, size_t ws_size,
                              hipStream_t stream) {
  if (ws_size < WS_NEEDED) return;
  const float* pc  = (const float*)d_in[0];
  const float* W1  = (const float*)d_in[1];
  const float* g1  = (const float*)d_in[2];
  const float* b1  = (const float*)d_in[3];
  const float* W2  = (const float*)d_in[4];
  const float* g2  = (const float*)d_in[5];
  const float* b2  = (const float*)d_in[6];
  const float* W3  = (const float*)d_in[7];
  const float* g3  = (const float*)d_in[8];
  const float* b3  = (const float*)d_in[9];
  const float* Wf1 = (const float*)d_in[10];
  const float* gf1 = (const float*)d_in[11];
  const float* bf1 = (const float*)d_in[12];
  const float* Wf2 = (const float*)d_in[13];
  const float* gf2 = (const float*)d_in[14];
  const float* bf2 = (const float*)d_in[15];
  const float* Wf3 = (const float*)d_in[16];
  const float* bf3 = (const float*)d_in[17];

  char* ws = (char*)d_ws;
  int*      IDX   = (int*)     (ws + OFF_IDX);
  short*    P2MAXp= (short*)   (ws + OFF_P2MAX);
  short*    P2MINp= (short*)   (ws + OFF_P2MIN);
  float*    PS2p  = (float*)   (ws + OFF_PS2);
  float*    PQ2p  = (float*)   (ws + OFF_PQ2);
  double*   MOMp  = (double*)  (ws + OFF_MOM);
  float*    A1C1p = (float*)   (ws + OFF_A1C1);
  float*    A2C2p = (float*)   (ws + OFF_A2C2);
  double*   S3SUMp= (double*)  (ws + OFF_S3SUM);
  double*   S3SQp = (double*)  (ws + OFF_S3SQ);
  unsigned* P3MAXp= (unsigned*)(ws + OFF_P3MAX);
  unsigned* P3MINp= (unsigned*)(ws + OFF_P3MIN);
  float*    R3p   = (float*)   (ws + OFF_R3);
  float*    R4p   = (float*)   (ws + OFF_R4);
  float*    R5p   = (float*)   (ws + OFF_R5);
  float*    DOTS1p= (float*)   (ws + OFF_DOTS1);
  float*    DOTS2p= (float*)   (ws + OFF_DOTS2);

  k_init          <<<dim3(64),       256, 0, stream>>>(ws);
  k_knn           <<<dim3(64,16),    256, 0, stream>>>(pc, IDX, MOMp);
  k_coef1         <<<dim3(1),         64, 0, stream>>>(MOMp, W1, g1, b1, A1C1p);
  k_conv12        <<<dim3(128,16),   256, 0, stream>>>(pc, IDX, A1C1p, W2, PS2p, PQ2p, P2MAXp, P2MINp);
  k_coef2         <<<dim3(128),      256, 0, stream>>>(PS2p, PQ2p, g2, b2, A2C2p);
  k_conv3         <<<dim3(16,16,2),  256, 0, stream>>>(P2MAXp, P2MINp, A2C2p, W3, S3SUMp, S3SQp, P3MAXp, P3MINp);
  k_bn3relu       <<<dim3(64),       256, 0, stream>>>(S3SUMp, S3SQp, P3MAXp, P3MINp, g3, b3, R3p);
  k_fcdot<1024,512><<<dim3(8,16),    256, 0, stream>>>(R3p, Wf1, DOTS1p);
  k_fcbn<512>     <<<dim3(8),         64, 0, stream>>>(DOTS1p, gf1, bf1, R4p);
  k_fcdot<512,256><<<dim3(4,16),     256, 0, stream>>>(R4p, Wf2, DOTS2p);
  k_fcbn<256>     <<<dim3(4),         64, 0, stream>>>(DOTS2p, gf2, bf2, R5p);
  k_head          <<<dim3(1),        192, 0, stream>>>(R5p, Wf3, bf3, (float*)d_out);
}